// Round 10
// baseline (628.831 us; speedup 1.0000x reference)
//
#include <hip/hip_runtime.h>
#include <math.h>

#define NN 40000
#define NPAD 40064   // 313 * 128
#define NE 640000
#define NG 40
#define NC 128
#define ND 256
#define SLOPEF 0.2f
#define EPSF 1e-5f
#define SCAN_NB 157  // ceil(40000/256)

typedef short bf16x8 __attribute__((ext_vector_type(8)));
typedef float f32x4 __attribute__((ext_vector_type(4)));

static __device__ __forceinline__ float lrelu(float x){ return x >= 0.0f ? x : SLOPEF * x; }

static __device__ __forceinline__ unsigned int bfpair(float a, float b){
  unsigned int ua = __float_as_uint(a);
  ua = (ua + 0x7fffu + ((ua >> 16) & 1u)) >> 16;
  unsigned int ub = __float_as_uint(b);
  ub = (ub + 0x7fffu + ((ub >> 16) & 1u)) >> 16;
  return ua | (ub << 16);
}
static __device__ __forceinline__ unsigned short bf1(float x){
  unsigned int u = __float_as_uint(x);
  return (unsigned short)((u + 0x7fffu + ((u >> 16) & 1u)) >> 16);
}
static __device__ __forceinline__ float4 cvt4(ushort4 v){
  float4 o;
  o.x = __uint_as_float(((unsigned)v.x) << 16);
  o.y = __uint_as_float(((unsigned)v.y) << 16);
  o.z = __uint_as_float(((unsigned)v.z) << 16);
  o.w = __uint_as_float(((unsigned)v.w) << 16);
  return o;
}

static __device__ __forceinline__ void gload16(const void* gsrc, void* lds){
  __builtin_amdgcn_global_load_lds(
      (const __attribute__((address_space(1))) void*)gsrc,
      (__attribute__((address_space(3))) void*)lds, 16, 0, 0);
}

// ---------------- consolidated zero-init ----------------
__global__ __launch_bounds__(256) void k_zero(int* __restrict__ deg, int* __restrict__ cur,
                                              int* __restrict__ cnt, int* __restrict__ gmn,
                                              int* __restrict__ gmx, float* __restrict__ gsum,
                                              float* __restrict__ gsq, float* __restrict__ obuf,
                                              int* __restrict__ ticket){
  int i = blockIdx.x*256 + threadIdx.x;
  int stride = gridDim.x*256;
  if(i == 0) *ticket = 0;
  for(int j = i; j < NN; j += stride){ deg[j] = 0; cur[j] = 0; }
  for(int j = i; j < NG; j += stride){ cnt[j] = 0; gmn[j] = 0x7f7f7f7f; gmx[j] = -1; }
  for(int j = i; j < NG*ND; j += stride){ gsum[j] = 0.0f; gsq[j] = 0.0f; }
  for(int j = i; j < NG*NC; j += stride){ obuf[j] = 0.0f; }
}

// ---------------- merged histogram: edge degree + graph count/min/max ----------------
__global__ __launch_bounds__(256) void k_hist(const int* __restrict__ dst, const int* __restrict__ gid,
                                              int* __restrict__ deg, int* __restrict__ cnt,
                                              int* __restrict__ gmn, int* __restrict__ gmx){
  __shared__ int lc[NG], lmn[NG], lmx[NG];
  int tid = threadIdx.x;
  for(int i = tid; i < NG; i += 256){ lc[i] = 0; lmn[i] = 0x7f7f7f7f; lmx[i] = -1; }
  __syncthreads();
  int stride = gridDim.x*256;
  int base = blockIdx.x*256 + tid;
  for(int n = base; n < NN; n += stride){
    int g = gid[n];
    atomicAdd(&lc[g], 1);
    atomicMin(&lmn[g], n);
    atomicMax(&lmx[g], n);
  }
  for(int e = base; e < NE; e += stride) atomicAdd(&deg[dst[e]], 1);
  __syncthreads();
  for(int i = tid; i < NG; i += 256){
    if(lc[i] > 0){
      atomicAdd(&cnt[i], lc[i]);
      atomicMin(&gmn[i], lmn[i]);
      atomicMax(&gmx[i], lmx[i]);
    }
  }
}

// -------- multi-block exclusive scan of deg[NN] -> rowstart[NN+1] --------
__global__ __launch_bounds__(256) void k_scan_a(const int* __restrict__ deg, int* __restrict__ bsum){
  int tid = threadIdx.x;
  int i = blockIdx.x*256 + tid;
  int v = (i < NN) ? deg[i] : 0;
#pragma unroll
  for(int off = 32; off >= 1; off >>= 1) v += __shfl_xor(v, off);
  __shared__ int ws[4];
  if((tid & 63) == 0) ws[tid >> 6] = v;
  __syncthreads();
  if(tid == 0) bsum[blockIdx.x] = ws[0] + ws[1] + ws[2] + ws[3];
}

__global__ __launch_bounds__(256) void k_scan_b(int* __restrict__ bsum, int* __restrict__ boff,
                                                int* __restrict__ rowstart){
  __shared__ int lds[256];
  int tid = threadIdx.x;
  int v = (tid < SCAN_NB) ? bsum[tid] : 0;
  lds[tid] = v;
  __syncthreads();
  for(int off = 1; off < 256; off <<= 1){
    int t = (tid >= off) ? lds[tid - off] : 0;
    __syncthreads();
    lds[tid] += t;
    __syncthreads();
  }
  if(tid < SCAN_NB) boff[tid] = lds[tid] - v;  // exclusive
  if(tid == SCAN_NB - 1) rowstart[NN] = lds[tid];
}

__global__ __launch_bounds__(256) void k_scan_c(const int* __restrict__ deg, const int* __restrict__ boff,
                                                int* __restrict__ rowstart){
  __shared__ int lds[256];
  int tid = threadIdx.x;
  int i = blockIdx.x*256 + tid;
  int v = (i < NN) ? deg[i] : 0;
  lds[tid] = v;
  __syncthreads();
  for(int off = 1; off < 256; off <<= 1){
    int t = (tid >= off) ? lds[tid - off] : 0;
    __syncthreads();
    lds[tid] += t;
    __syncthreads();
  }
  if(i < NN) rowstart[i] = boff[blockIdx.x] + lds[tid] - v;
}

__global__ void k_fill(const int* __restrict__ src, const int* __restrict__ dst,
                       const int* __restrict__ rowstart, int* __restrict__ cur, int* __restrict__ srcS){
  int e = blockIdx.x*256 + threadIdx.x;
  if(e < NE){
    int d = dst[e];
    int slot = rowstart[d] + atomicAdd(&cur[d], 1);
    srcS[slot] = src[e];
  }
}

// ---------------- upfront prep: X0->bf16 A, all weight transposes ----------------
#define PREP_A  (NPAD*NC/8)          // 641024
#define PREP_W0 (2*ND*NC/8)          // 8192
#define PREP_W  (ND*ND/8)            // 8192
__global__ __launch_bounds__(256) void k_prep(const float* __restrict__ X0,
                                              const float* __restrict__ W0, const float* __restrict__ Wr,
                                              const float* __restrict__ W1, const float* __restrict__ W2,
                                              unsigned int* __restrict__ A0,
                                              unsigned short* __restrict__ Bt0,
                                              unsigned short* __restrict__ Bt1,
                                              unsigned short* __restrict__ Bt2){
  int total = PREP_A + PREP_W0 + 2*PREP_W;
  for(int i = blockIdx.x*256 + threadIdx.x; i < total; i += gridDim.x*256){
    if(i < PREP_A){
      long e8 = (long)i * 8;
      int row = (int)(e8 / NC);
      int col = (int)(e8 - (long)row * NC);
      uint4 o;
      if(row < NN){
        const float4* p = (const float4*)(X0 + (size_t)row*NC + col);
        float4 v0 = p[0], v1 = p[1];
        o.x = bfpair(v0.x, v0.y); o.y = bfpair(v0.z, v0.w);
        o.z = bfpair(v1.x, v1.y); o.w = bfpair(v1.z, v1.w);
      } else o = make_uint4(0,0,0,0);
      ((uint4*)A0)[i] = o;
    } else if(i < PREP_A + PREP_W0){
      int j = i - PREP_A;
      int c = j >> 4;                 // NC/8 = 16
      int k0 = (j & 15) * 8;
      const float* W = (c < ND) ? W0 : Wr;
      int cc = c & (ND-1);
      float v[8];
#pragma unroll
      for(int u = 0; u < 8; ++u) v[u] = W[(size_t)(k0+u)*ND + cc];
      uint4 o;
      o.x = bfpair(v[0], v[1]); o.y = bfpair(v[2], v[3]);
      o.z = bfpair(v[4], v[5]); o.w = bfpair(v[6], v[7]);
      *((uint4*)(Bt0 + (size_t)c*NC + k0)) = o;
    } else {
      int j = i - PREP_A - PREP_W0;
      const float* W = (j < PREP_W) ? W1 : W2;
      unsigned short* Bt = (j < PREP_W) ? Bt1 : Bt2;
      j &= (PREP_W - 1);
      int c = j >> 5;                 // ND/8 = 32
      int k0 = (j & 31) * 8;
      float v[8];
#pragma unroll
      for(int u = 0; u < 8; ++u) v[u] = W[(size_t)(k0+u)*ND + c];
      uint4 o;
      o.x = bfpair(v[0], v[1]); o.y = bfpair(v[2], v[3]);
      o.z = bfpair(v[4], v[5]); o.w = bfpair(v[6], v[7]);
      *((uint4*)(Bt + (size_t)c*ND + k0)) = o;
    }
  }
}

// ---------------- bf16 MFMA GEMM ----------------
// MODE 1: bf16 out to Cb[NN][ND].  MODE 2 (L0): cols<ND -> Cb (h); cols>=ND -> Cb2 (bf16 residual).
template<int K, int MODE>
__global__ __launch_bounds__(256) void k_gemm_bf16(const unsigned short* __restrict__ A,
                                                   const unsigned short* __restrict__ Bt,
                                                   unsigned short* __restrict__ Cb2,
                                                   unsigned short* __restrict__ Cb){
  __shared__ unsigned short As[128*32];
  __shared__ unsigned short Bs[128*32];
  int t = threadIdx.x;
  int lane = t & 63, wid = t >> 6;
  int wm = wid & 1, wn = wid >> 1;
  int r = lane & 15, g = lane >> 4;
  int bm = blockIdx.x * 128;
  int bn = blockIdx.y * 128;
  int srow = t >> 2, scol = (t & 3) * 8;

  int aoff[4], boff[4];
#pragma unroll
  for(int m = 0; m < 4; ++m) aoff[m] = ((wm*64 + m*16 + r) << 5) + (g << 3);
#pragma unroll
  for(int n = 0; n < 4; ++n) boff[n] = ((wn*64 + n*16 + r) << 5) + (g << 3);

  f32x4 acc[4][4] = {};

  for(int k0 = 0; k0 < K; k0 += 32){
    gload16(A + (size_t)(bm + srow)*K      + k0 + scol, (char*)As + t*16);
    gload16(A + (size_t)(bm + 64 + srow)*K + k0 + scol, (char*)As + 4096 + t*16);
    gload16(Bt + (size_t)(bn + srow)*K      + k0 + scol, (char*)Bs + t*16);
    gload16(Bt + (size_t)(bn + 64 + srow)*K + k0 + scol, (char*)Bs + 4096 + t*16);
    __syncthreads();

    bf16x8 af[4], bfv[4];
#pragma unroll
    for(int m = 0; m < 4; ++m) af[m] = *(const bf16x8*)&As[aoff[m]];
#pragma unroll
    for(int n = 0; n < 4; ++n) bfv[n] = *(const bf16x8*)&Bs[boff[n]];
#pragma unroll
    for(int m = 0; m < 4; ++m)
#pragma unroll
      for(int n = 0; n < 4; ++n)
        acc[m][n] = __builtin_amdgcn_mfma_f32_16x16x32_bf16(af[m], bfv[n], acc[m][n], 0, 0, 0);
    __syncthreads();
  }

#pragma unroll
  for(int m = 0; m < 4; ++m){
    int row0 = bm + wm*64 + m*16 + g*4;
#pragma unroll
    for(int n = 0; n < 4; ++n){
      int col = bn + wn*64 + n*16 + r;
#pragma unroll
      for(int i = 0; i < 4; ++i){
        if(row0 + i < NN){
          if(MODE == 1){
            Cb[(size_t)(row0+i)*ND + col] = bf1(acc[m][n][i]);
          } else {
            if(col < ND) Cb[(size_t)(row0+i)*ND + col] = bf1(acc[m][n][i]);
            else         Cb2[(size_t)(row0+i)*ND + (col - ND)] = bf1(acc[m][n][i]);
          }
        }
      }
    }
  }
}

// ---------------- el/er from bf16 h ----------------
__global__ __launch_bounds__(256) void k_elr(const unsigned short* __restrict__ Hm, const float* __restrict__ al,
                                             const float* __restrict__ ar, float* __restrict__ el,
                                             float* __restrict__ er){
  int n = blockIdx.x*4 + (threadIdx.x >> 6);
  int lane = threadIdx.x & 63;
  if(n >= NN) return;
  float4 hv = cvt4(((const ushort4*)(Hm + (size_t)n*ND))[lane]);
  float4 a  = ((const float4*)al)[lane];
  float4 b  = ((const float4*)ar)[lane];
  float sl = hv.x*a.x + hv.y*a.y + hv.z*a.z + hv.w*a.w;
  float sr = hv.x*b.x + hv.y*b.y + hv.z*b.z + hv.w*b.w;
#pragma unroll
  for(int off = 16; off >= 1; off >>= 1){ sl += __shfl_xor(sl, off); sr += __shfl_xor(sr, off); }
  if(lane == 0){ el[n*2+0] = sl; er[n*2+0] = sr; }
  if(lane == 32){ el[n*2+1] = sl; er[n*2+1] = sr; }
}

// ---------------- attention softmax + aggregate (one wave per dst node, 4-deep gather pipeline) ----------------
// bf16 residual in, bf16 out. All __shfl at FULL exec (R5/R6 lesson); select AFTER shuffles.
__global__ __launch_bounds__(256) void k_attn(const unsigned short* __restrict__ Hm, const float* __restrict__ el,
                                              const float* __restrict__ er, const int* __restrict__ rowstart,
                                              const int* __restrict__ srcS, const unsigned short* __restrict__ res,
                                              unsigned short* __restrict__ out){
  int n = blockIdx.x*4 + (threadIdx.x >> 6);
  int lane = threadIdx.x & 63;
  if(n >= NN) return;
  int rs = rowstart[n], re = rowstart[n+1];
  int deg = re - rs;
  float4 acc = cvt4(((const ushort4*)(res + (size_t)n*ND))[lane]);
  if(deg > 0){
    float er0 = er[n*2], er1 = er[n*2+1];
    if(deg <= 64){
      int s = srcS[rs + (lane < deg ? lane : 0)];
      float e0 = -1e30f, e1 = -1e30f;
      if(lane < deg){
        e0 = lrelu(el[s*2]   + er0);
        e1 = lrelu(el[s*2+1] + er1);
      }
      float m0 = e0, m1 = e1;
#pragma unroll
      for(int off = 32; off >= 1; off >>= 1){ m0 = fmaxf(m0, __shfl_xor(m0, off)); m1 = fmaxf(m1, __shfl_xor(m1, off)); }
      float x0 = (lane < deg) ? expf(e0 - m0) : 0.0f;
      float x1 = (lane < deg) ? expf(e1 - m1) : 0.0f;
      float s0 = x0, s1 = x1;
#pragma unroll
      for(int off = 32; off >= 1; off >>= 1){ s0 += __shfl_xor(s0, off); s1 += __shfl_xor(s1, off); }
      x0 *= 1.0f/(s0 + 1e-9f);
      x1 *= 1.0f/(s1 + 1e-9f);
      bool h1 = (lane >= 32);
      for(int j0 = 0; j0 < deg; j0 += 4){
        int sj0 = __shfl(s, j0+0), sj1 = __shfl(s, j0+1);
        int sj2 = __shfl(s, j0+2), sj3 = __shfl(s, j0+3);
        ushort4 g0 = ((const ushort4*)(Hm + (size_t)sj0*ND))[lane];
        ushort4 g1 = ((const ushort4*)(Hm + (size_t)sj1*ND))[lane];
        ushort4 g2 = ((const ushort4*)(Hm + (size_t)sj2*ND))[lane];
        ushort4 g3 = ((const ushort4*)(Hm + (size_t)sj3*ND))[lane];
        float a00 = __shfl(x0, j0+0), a10 = __shfl(x1, j0+0);
        float a01 = __shfl(x0, j0+1), a11 = __shfl(x1, j0+1);
        float a02 = __shfl(x0, j0+2), a12 = __shfl(x1, j0+2);
        float a03 = __shfl(x0, j0+3), a13 = __shfl(x1, j0+3);
        float w0 = h1 ? a10 : a00;
        float w1 = h1 ? a11 : a01;
        float w2 = h1 ? a12 : a02;
        float w3 = h1 ? a13 : a03;
        float4 v0 = cvt4(g0), v1 = cvt4(g1), v2 = cvt4(g2), v3 = cvt4(g3);
        acc.x += w0*v0.x + w1*v1.x + w2*v2.x + w3*v3.x;
        acc.y += w0*v0.y + w1*v1.y + w2*v2.y + w3*v3.y;
        acc.z += w0*v0.z + w1*v1.z + w2*v2.z + w3*v3.z;
        acc.w += w0*v0.w + w1*v1.w + w2*v2.w + w3*v3.w;
      }
    } else {
      float m0 = -1e30f, m1 = -1e30f;
      for(int j = lane; j < deg; j += 64){
        int s = srcS[rs + j];
        m0 = fmaxf(m0, lrelu(el[s*2]   + er0));
        m1 = fmaxf(m1, lrelu(el[s*2+1] + er1));
      }
#pragma unroll
      for(int off = 32; off >= 1; off >>= 1){ m0 = fmaxf(m0, __shfl_xor(m0, off)); m1 = fmaxf(m1, __shfl_xor(m1, off)); }
      float s0 = 0.0f, s1 = 0.0f;
      for(int j = lane; j < deg; j += 64){
        int s = srcS[rs + j];
        s0 += expf(lrelu(el[s*2]   + er0) - m0);
        s1 += expf(lrelu(el[s*2+1] + er1) - m1);
      }
#pragma unroll
      for(int off = 32; off >= 1; off >>= 1){ s0 += __shfl_xor(s0, off); s1 += __shfl_xor(s1, off); }
      float inv = (lane < 32) ? 1.0f/(s0 + 1e-9f) : 1.0f/(s1 + 1e-9f);
      float mh  = (lane < 32) ? m0 : m1;
      for(int j = 0; j < deg; ++j){
        int s = srcS[rs + j];
        float e = (lane < 32) ? lrelu(el[s*2] + er0) : lrelu(el[s*2+1] + er1);
        float a = expf(e - mh) * inv;
        float4 hv = cvt4(((const ushort4*)(Hm + (size_t)s*ND))[lane]);
        acc.x += a*hv.x; acc.y += a*hv.y; acc.z += a*hv.z; acc.w += a*hv.w;
      }
    }
  }
  uint2 pk; pk.x = bfpair(acc.x, acc.y); pk.y = bfpair(acc.z, acc.w);
  ((uint2*)(out + (size_t)n*ND))[lane] = pk;
}

// ---------------- per-graph column stats (bf16 input) + fused finstats via last-block ticket ----------------
__global__ __launch_bounds__(256) void k_gstats(const unsigned short* __restrict__ X, const int* __restrict__ gid,
                                                float* __restrict__ gsum, float* __restrict__ gsq,
                                                const int* __restrict__ cnt, float* __restrict__ gmean,
                                                float* __restrict__ grs, float* __restrict__ bnm,
                                                float* __restrict__ bnrs, int* __restrict__ ticket){
  __shared__ f32x4 reds[256];
  __shared__ f32x4 redq[256];
  int tid = threadIdx.x;
  int f4 = tid & 63;
  int r  = tid >> 6;
  int n0 = blockIdx.x * 125;
  int g0 = gid[n0];
  f32x4 s0 = {0,0,0,0}, q0 = {0,0,0,0};
  f32x4 s1 = {0,0,0,0}, q1 = {0,0,0,0};
  int cg1 = -1;
  for(int n = n0 + r; n < n0 + 125; n += 4){
    int g = gid[n];
    float4 vv = cvt4(*(const ushort4*)(X + (size_t)n*ND + f4*4));
    f32x4 v = {vv.x, vv.y, vv.z, vv.w};
    if(g == g0){ s0 += v; q0 += v*v; }
    else {
      if(g != cg1){
        if(cg1 >= 0){
#pragma unroll
          for(int j = 0; j < 4; ++j){
            atomicAdd(&gsum[cg1*ND + f4*4 + j], s1[j]);
            atomicAdd(&gsq [cg1*ND + f4*4 + j], q1[j]);
          }
        }
        cg1 = g; s1 = (f32x4){0,0,0,0}; q1 = (f32x4){0,0,0,0};
      }
      s1 += v; q1 += v*v;
    }
  }
  if(cg1 >= 0){
#pragma unroll
    for(int j = 0; j < 4; ++j){
      atomicAdd(&gsum[cg1*ND + f4*4 + j], s1[j]);
      atomicAdd(&gsq [cg1*ND + f4*4 + j], q1[j]);
    }
  }
  reds[tid] = s0; redq[tid] = q0;
  __syncthreads();
  if(r == 0){
    f32x4 ts = reds[f4] + reds[f4+64] + reds[f4+128] + reds[f4+192];
    f32x4 tq = redq[f4] + redq[f4+64] + redq[f4+128] + redq[f4+192];
#pragma unroll
    for(int j = 0; j < 4; ++j){
      atomicAdd(&gsum[g0*ND + f4*4 + j], ts[j]);
      atomicAdd(&gsq [g0*ND + f4*4 + j], tq[j]);
    }
  }
  // ---- last block computes finstats (device-scope atomic reads; self-resets for next layer) ----
  __threadfence();
  __shared__ int lastFlag;
  if(tid == 0) lastFlag = (atomicAdd(ticket, 1) == (int)gridDim.x - 1) ? 1 : 0;
  __syncthreads();
  if(lastFlag){
    int d = tid; // 256 threads = 256 cols
    float ts = 0.0f, tq = 0.0f;
    for(int g = 0; g < NG; ++g){
      float c = (float)cnt[g];
      float s = atomicAdd(&gsum[g*ND + d], 0.0f);   // coherent read past per-XCD L2
      float q = atomicAdd(&gsq [g*ND + d], 0.0f);
      gsum[g*ND + d] = 0.0f; gsq[g*ND + d] = 0.0f;  // reset for next layer (flushed at kernel end)
      ts += s; tq += q;
      float m = s / c;
      float v = q / c - m*m;
      gmean[g*ND + d] = m;
      grs[g*ND + d] = rsqrtf(fmaxf(v, 0.0f) + EPSF);
    }
    float bm = ts / (float)NN;
    float bv = tq / (float)NN - bm*bm;
    bnm[d] = bm;
    bnrs[d] = rsqrtf(fmaxf(bv, 0.0f) + EPSF);
    if(d == 0) *ticket = 0;
  }
}

// ---------------- united norm apply (+ leaky) ----------------
// bf16 X in. LAYER<2: single bf16 out (residual AND next GEMM A, pad rows zeroed).
// LAYER==2: fp32 head_mean out.
template<int LAYER>
__global__ __launch_bounds__(256) void k_norm(const unsigned short* __restrict__ X, const int* __restrict__ gid,
    const float* __restrict__ gmean, const float* __restrict__ grs, const float* __restrict__ bnm,
    const float* __restrict__ bnrs, const float* __restrict__ gamma, const float* __restrict__ beta,
    const float* __restrict__ lbn, const float* __restrict__ lgn, const float* __restrict__ lnn,
    unsigned short* __restrict__ outb, float* __restrict__ outf){
  int n = blockIdx.x*4 + (threadIdx.x >> 6);
  int lane = threadIdx.x & 63;
  if(n >= NPAD) return;
  if(n >= NN){
    if(LAYER < 2){ uint2 z = {0,0}; ((uint2*)(outb + (size_t)n*ND))[lane] = z; }
    return;
  }
  float4 v = cvt4(((const ushort4*)(X + (size_t)n*ND))[lane]);
  float s = v.x + v.y + v.z + v.w;
  float q = v.x*v.x + v.y*v.y + v.z*v.z + v.w*v.w;
#pragma unroll
  for(int off = 32; off >= 1; off >>= 1){ s += __shfl_xor(s, off); q += __shfl_xor(q, off); }
  float nm = s * (1.0f/ND);
  float nv = q * (1.0f/ND) - nm*nm;
  float nrs = rsqrtf(fmaxf(nv, 0.0f) + EPSF);
  int g = gid[n];
  float4 gm = ((const float4*)(gmean + g*ND))[lane];
  float4 gr = ((const float4*)(grs   + g*ND))[lane];
  float4 bm = ((const float4*)bnm)[lane];
  float4 br = ((const float4*)bnrs)[lane];
  float4 ga = ((const float4*)gamma)[lane];
  float4 be = ((const float4*)beta)[lane];
  float4 lb = ((const float4*)lbn)[lane];
  float4 lg = ((const float4*)lgn)[lane];
  float4 ln = ((const float4*)lnn)[lane];
  float4 o;
  o.x = lrelu(ga.x*(lb.x*((v.x-bm.x)*br.x) + lg.x*((v.x-gm.x)*gr.x) + ln.x*((v.x-nm)*nrs)) + be.x);
  o.y = lrelu(ga.y*(lb.y*((v.y-bm.y)*br.y) + lg.y*((v.y-gm.y)*gr.y) + ln.y*((v.y-nm)*nrs)) + be.y);
  o.z = lrelu(ga.z*(lb.z*((v.z-bm.z)*br.z) + lg.z*((v.z-gm.z)*gr.z) + ln.z*((v.z-nm)*nrs)) + be.z);
  o.w = lrelu(ga.w*(lb.w*((v.w-bm.w)*br.w) + lg.w*((v.w-gm.w)*gr.w) + ln.w*((v.w-nm)*nrs)) + be.w);
  if(LAYER < 2){
    uint2 pk; pk.x = bfpair(o.x, o.y); pk.y = bfpair(o.z, o.w);
    ((uint2*)(outb + (size_t)n*ND))[lane] = pk;
  } else {
    float4 p;
    p.x = __shfl_xor(o.x, 32); p.y = __shfl_xor(o.y, 32);
    p.z = __shfl_xor(o.z, 32); p.w = __shfl_xor(o.w, 32);
    if(lane < 32){
      float4 hm;
      hm.x = 0.5f*(o.x + p.x); hm.y = 0.5f*(o.y + p.y);
      hm.z = 0.5f*(o.z + p.z); hm.w = 0.5f*(o.w + p.w);
      ((float4*)(outf + (size_t)n*NC))[lane] = hm;
    }
  }
}

// ---------------- graph readout ----------------
__global__ void k_readout_part(const float* __restrict__ HM, const int* __restrict__ gid,
                               const int* __restrict__ gmn, const int* __restrict__ gmx,
                               float* __restrict__ obuf){
  int g = blockIdx.x >> 3, part = blockIdx.x & 7;
  int c = threadIdx.x; // 128
  int n0 = gmn[g], n1 = gmx[g] + 1;
  int len = n1 - n0;
  int beg = n0 + (int)(((long)len * part) >> 3);
  int end = n0 + (int)(((long)len * (part+1)) >> 3);
  float acc = 0.0f;
  for(int n = beg; n < end; ++n){
    if(gid[n] == g) acc += HM[(size_t)n*NC + c];
  }
  atomicAdd(&obuf[g*NC + c], acc);
}

__global__ void k_readout_fin(const float* __restrict__ obuf, const int* __restrict__ cnt,
                              float* __restrict__ outp){
  int i = blockIdx.x*128 + threadIdx.x; // NG*NC
  int g = i / NC;
  outp[i] = lrelu(obuf[i] / (float)cnt[g]);
}

// ---------------- launch ----------------
extern "C" void kernel_launch(void* const* d_in, const int* in_sizes, int n_in,
                              void* d_out, int out_size, void* d_ws, size_t ws_size,
                              hipStream_t stream){
  const float* X0  = (const float*)d_in[0];
  const int* src   = (const int*)d_in[1];
  const int* dst   = (const int*)d_in[2];
  const int* gid   = (const int*)d_in[3];
  const float* Wm[3] = { (const float*)d_in[4], (const float*)d_in[5], (const float*)d_in[6] };
  const float* resW  = (const float*)d_in[7];
  const float *AL[3], *AR[3], *GA[3], *BE[3], *LB[3], *LG[3], *LN[3];
  for(int i = 0; i < 3; ++i){
    int b = 8 + i*7;
    AL[i] = (const float*)d_in[b];   AR[i] = (const float*)d_in[b+1];
    GA[i] = (const float*)d_in[b+2]; BE[i] = (const float*)d_in[b+3];
    LB[i] = (const float*)d_in[b+4]; LG[i] = (const float*)d_in[b+5]; LN[i] = (const float*)d_in[b+6];
  }
  float* out = (float*)d_out;

  // workspace layout (all node-feature intermediates bf16)
  float* wf = (float*)d_ws;
  unsigned short* Hbf  = (unsigned short*)wf;  wf += (size_t)NN*ND/2;    // h bf16
  unsigned short* XAb  = (unsigned short*)wf;  wf += (size_t)NN*ND/2;    // attn out bf16; L0 A-staging
  unsigned short* XBb  = (unsigned short*)wf;  wf += (size_t)NPAD*ND/2;  // norm out bf16 (residual + GEMM A)
  unsigned short* RESb = (unsigned short*)wf;  wf += (size_t)NN*ND/2;    // L0 residual bf16; later head_mean fp32
  float* el   = wf;                 wf += (size_t)NN*2;
  float* er   = wf;                 wf += (size_t)NN*2;
  float* gsum = wf;                 wf += NG*ND;
  float* gsq  = wf;                 wf += NG*ND;
  float* gmean= wf;                 wf += NG*ND;
  float* grs  = wf;                 wf += NG*ND;
  float* bnm  = wf;                 wf += ND;
  float* bnrs = wf;                 wf += ND;
  float* obuf = wf;                 wf += NG*NC;
  unsigned short* Bt0 = (unsigned short*)wf; wf += (2*ND*NC)/2;   // 512x128 bf16
  unsigned short* Bt1 = (unsigned short*)wf; wf += (ND*ND)/2;     // 256x256 bf16
  unsigned short* Bt2 = (unsigned short*)wf; wf += (ND*ND)/2;     // 256x256 bf16
  int* ip = (int*)wf;
  int* deg      = ip;               ip += NN;
  int* rowstart = ip;               ip += NN + 1;
  int* cur      = ip;               ip += NN;
  int* srcS     = ip;               ip += NE;
  int* cnt      = ip;               ip += NG;
  int* gmn      = ip;               ip += NG;
  int* gmx      = ip;               ip += NG;
  int* bsum     = ip;               ip += SCAN_NB;
  int* boff     = ip;               ip += SCAN_NB;
  int* ticket   = ip;               ip += 1;

  unsigned short* A0bf = XAb;            // L0 bf16 A staging (GEMM consumes before attn overwrites)
  float* HMf = (float*)RESb;             // L2 head_mean fp32 (NN*NC floats fit in NN*ND/2 ushort slots)

  // ---- init + prep + CSR + graph meta ----
  k_zero<<<SCAN_NB, 256, 0, stream>>>(deg, cur, cnt, gmn, gmx, gsum, gsq, obuf, ticket);
  k_prep<<<2600, 256, 0, stream>>>(X0, Wm[0], resW, Wm[1], Wm[2], (unsigned int*)A0bf, Bt0, Bt1, Bt2);
  k_hist<<<2500, 256, 0, stream>>>(dst, gid, deg, cnt, gmn, gmx);
  k_scan_a<<<SCAN_NB, 256, 0, stream>>>(deg, bsum);
  k_scan_b<<<1, 256, 0, stream>>>(bsum, boff, rowstart);
  k_scan_c<<<SCAN_NB, 256, 0, stream>>>(deg, boff, rowstart);
  k_fill<<<(NE+255)/256, 256, 0, stream>>>(src, dst, rowstart, cur, srcS);

  for(int L = 0; L < 3; ++L){
    if(L == 0){
      dim3 g0(NPAD/128, 4);  // cols 0..255 -> Hbf, 256..511 -> RESb (bf16 residual)
      k_gemm_bf16<NC,2><<<g0, 256, 0, stream>>>(A0bf, Bt0, RESb, Hbf);
    } else {
      dim3 g1(NPAD/128, 2);
      k_gemm_bf16<ND,1><<<g1, 256, 0, stream>>>(XBb, (L == 1) ? Bt1 : Bt2, nullptr, Hbf);
    }
    const unsigned short* resp = (L == 0) ? RESb : XBb;
    k_elr<<<NN/4, 256, 0, stream>>>(Hbf, AL[L], AR[L], el, er);
    k_attn<<<NN/4, 256, 0, stream>>>(Hbf, el, er, rowstart, srcS, resp, XAb);
    k_gstats<<<NN/125, 256, 0, stream>>>(XAb, gid, gsum, gsq, cnt, gmean, grs, bnm, bnrs, ticket);
    if(L == 0)      k_norm<0><<<NPAD/4, 256, 0, stream>>>(XAb, gid, gmean, grs, bnm, bnrs, GA[0], BE[0], LB[0], LG[0], LN[0], XBb, nullptr);
    else if(L == 1) k_norm<1><<<NPAD/4, 256, 0, stream>>>(XAb, gid, gmean, grs, bnm, bnrs, GA[1], BE[1], LB[1], LG[1], LN[1], XBb, nullptr);
    else            k_norm<2><<<NN/4, 256, 0, stream>>>(XAb, gid, gmean, grs, bnm, bnrs, GA[2], BE[2], LB[2], LG[2], LN[2], nullptr, HMf);
  }
  k_readout_part<<<NG*8, NC, 0, stream>>>(HMf, gid, gmn, gmx, obuf);
  k_readout_fin<<<NG, NC, 0, stream>>>(obuf, cnt, out);
}

// Round 11
// 464.792 us; speedup vs baseline: 1.3529x; 1.3529x over previous
//
#include <hip/hip_runtime.h>
#include <math.h>

#define NN 40000
#define NPAD 40064   // 313 * 128
#define NE 640000
#define NG 40
#define NC 128
#define ND 256
#define SLOPEF 0.2f
#define EPSF 1e-5f
#define SCAN_NB 157  // ceil(40000/256)

typedef short bf16x8 __attribute__((ext_vector_type(8)));
typedef float f32x4 __attribute__((ext_vector_type(4)));

static __device__ __forceinline__ float lrelu(float x){ return x >= 0.0f ? x : SLOPEF * x; }

static __device__ __forceinline__ unsigned int bfpair(float a, float b){
  unsigned int ua = __float_as_uint(a);
  ua = (ua + 0x7fffu + ((ua >> 16) & 1u)) >> 16;
  unsigned int ub = __float_as_uint(b);
  ub = (ub + 0x7fffu + ((ub >> 16) & 1u)) >> 16;
  return ua | (ub << 16);
}
static __device__ __forceinline__ unsigned short bf1(float x){
  unsigned int u = __float_as_uint(x);
  return (unsigned short)((u + 0x7fffu + ((u >> 16) & 1u)) >> 16);
}
static __device__ __forceinline__ float4 cvt4(ushort4 v){
  float4 o;
  o.x = __uint_as_float(((unsigned)v.x) << 16);
  o.y = __uint_as_float(((unsigned)v.y) << 16);
  o.z = __uint_as_float(((unsigned)v.z) << 16);
  o.w = __uint_as_float(((unsigned)v.w) << 16);
  return o;
}

static __device__ __forceinline__ void gload16(const void* gsrc, void* lds){
  __builtin_amdgcn_global_load_lds(
      (const __attribute__((address_space(1))) void*)gsrc,
      (__attribute__((address_space(3))) void*)lds, 16, 0, 0);
}

// ---------------- consolidated zero-init ----------------
__global__ __launch_bounds__(256) void k_zero(int* __restrict__ deg, int* __restrict__ cur,
                                              int* __restrict__ cnt, int* __restrict__ gmn,
                                              int* __restrict__ gmx, float* __restrict__ gsum,
                                              float* __restrict__ gsq, float* __restrict__ obuf){
  int i = blockIdx.x*256 + threadIdx.x;
  int stride = gridDim.x*256;
  for(int j = i; j < NN; j += stride){ deg[j] = 0; cur[j] = 0; }
  for(int j = i; j < NG; j += stride){ cnt[j] = 0; gmn[j] = 0x7f7f7f7f; gmx[j] = -1; }
  for(int j = i; j < NG*ND; j += stride){ gsum[j] = 0.0f; gsq[j] = 0.0f; }
  for(int j = i; j < NG*NC; j += stride){ obuf[j] = 0.0f; }
}

// ---------------- merged histogram: edge degree + graph count/min/max ----------------
__global__ __launch_bounds__(256) void k_hist(const int* __restrict__ dst, const int* __restrict__ gid,
                                              int* __restrict__ deg, int* __restrict__ cnt,
                                              int* __restrict__ gmn, int* __restrict__ gmx){
  __shared__ int lc[NG], lmn[NG], lmx[NG];
  int tid = threadIdx.x;
  for(int i = tid; i < NG; i += 256){ lc[i] = 0; lmn[i] = 0x7f7f7f7f; lmx[i] = -1; }
  __syncthreads();
  int stride = gridDim.x*256;
  int base = blockIdx.x*256 + tid;
  for(int n = base; n < NN; n += stride){
    int g = gid[n];
    atomicAdd(&lc[g], 1);
    atomicMin(&lmn[g], n);
    atomicMax(&lmx[g], n);
  }
  for(int e = base; e < NE; e += stride) atomicAdd(&deg[dst[e]], 1);
  __syncthreads();
  for(int i = tid; i < NG; i += 256){
    if(lc[i] > 0){
      atomicAdd(&cnt[i], lc[i]);
      atomicMin(&gmn[i], lmn[i]);
      atomicMax(&gmx[i], lmx[i]);
    }
  }
}

// -------- multi-block exclusive scan of deg[NN] -> rowstart[NN+1] --------
__global__ __launch_bounds__(256) void k_scan_a(const int* __restrict__ deg, int* __restrict__ bsum){
  int tid = threadIdx.x;
  int i = blockIdx.x*256 + tid;
  int v = (i < NN) ? deg[i] : 0;
#pragma unroll
  for(int off = 32; off >= 1; off >>= 1) v += __shfl_xor(v, off);
  __shared__ int ws[4];
  if((tid & 63) == 0) ws[tid >> 6] = v;
  __syncthreads();
  if(tid == 0) bsum[blockIdx.x] = ws[0] + ws[1] + ws[2] + ws[3];
}

__global__ __launch_bounds__(256) void k_scan_b(int* __restrict__ bsum, int* __restrict__ boff,
                                                int* __restrict__ rowstart){
  __shared__ int lds[256];
  int tid = threadIdx.x;
  int v = (tid < SCAN_NB) ? bsum[tid] : 0;
  lds[tid] = v;
  __syncthreads();
  for(int off = 1; off < 256; off <<= 1){
    int t = (tid >= off) ? lds[tid - off] : 0;
    __syncthreads();
    lds[tid] += t;
    __syncthreads();
  }
  if(tid < SCAN_NB) boff[tid] = lds[tid] - v;  // exclusive
  if(tid == SCAN_NB - 1) rowstart[NN] = lds[tid];
}

__global__ __launch_bounds__(256) void k_scan_c(const int* __restrict__ deg, const int* __restrict__ boff,
                                                int* __restrict__ rowstart){
  __shared__ int lds[256];
  int tid = threadIdx.x;
  int i = blockIdx.x*256 + tid;
  int v = (i < NN) ? deg[i] : 0;
  lds[tid] = v;
  __syncthreads();
  for(int off = 1; off < 256; off <<= 1){
    int t = (tid >= off) ? lds[tid - off] : 0;
    __syncthreads();
    lds[tid] += t;
    __syncthreads();
  }
  if(i < NN) rowstart[i] = boff[blockIdx.x] + lds[tid] - v;
}

__global__ void k_fill(const int* __restrict__ src, const int* __restrict__ dst,
                       const int* __restrict__ rowstart, int* __restrict__ cur, int* __restrict__ srcS){
  int e = blockIdx.x*256 + threadIdx.x;
  if(e < NE){
    int d = dst[e];
    int slot = rowstart[d] + atomicAdd(&cur[d], 1);
    srcS[slot] = src[e];
  }
}

// ---------------- upfront prep: X0->bf16 A, all weight transposes ----------------
#define PREP_A  (NPAD*NC/8)          // 641024
#define PREP_W0 (2*ND*NC/8)          // 8192
#define PREP_W  (ND*ND/8)            // 8192
__global__ __launch_bounds__(256) void k_prep(const float* __restrict__ X0,
                                              const float* __restrict__ W0, const float* __restrict__ Wr,
                                              const float* __restrict__ W1, const float* __restrict__ W2,
                                              unsigned int* __restrict__ A0,
                                              unsigned short* __restrict__ Bt0,
                                              unsigned short* __restrict__ Bt1,
                                              unsigned short* __restrict__ Bt2){
  int total = PREP_A + PREP_W0 + 2*PREP_W;
  for(int i = blockIdx.x*256 + threadIdx.x; i < total; i += gridDim.x*256){
    if(i < PREP_A){
      long e8 = (long)i * 8;
      int row = (int)(e8 / NC);
      int col = (int)(e8 - (long)row * NC);
      uint4 o;
      if(row < NN){
        const float4* p = (const float4*)(X0 + (size_t)row*NC + col);
        float4 v0 = p[0], v1 = p[1];
        o.x = bfpair(v0.x, v0.y); o.y = bfpair(v0.z, v0.w);
        o.z = bfpair(v1.x, v1.y); o.w = bfpair(v1.z, v1.w);
      } else o = make_uint4(0,0,0,0);
      ((uint4*)A0)[i] = o;
    } else if(i < PREP_A + PREP_W0){
      int j = i - PREP_A;
      int c = j >> 4;                 // NC/8 = 16
      int k0 = (j & 15) * 8;
      const float* W = (c < ND) ? W0 : Wr;
      int cc = c & (ND-1);
      float v[8];
#pragma unroll
      for(int u = 0; u < 8; ++u) v[u] = W[(size_t)(k0+u)*ND + cc];
      uint4 o;
      o.x = bfpair(v[0], v[1]); o.y = bfpair(v[2], v[3]);
      o.z = bfpair(v[4], v[5]); o.w = bfpair(v[6], v[7]);
      *((uint4*)(Bt0 + (size_t)c*NC + k0)) = o;
    } else {
      int j = i - PREP_A - PREP_W0;
      const float* W = (j < PREP_W) ? W1 : W2;
      unsigned short* Bt = (j < PREP_W) ? Bt1 : Bt2;
      j &= (PREP_W - 1);
      int c = j >> 5;                 // ND/8 = 32
      int k0 = (j & 31) * 8;
      float v[8];
#pragma unroll
      for(int u = 0; u < 8; ++u) v[u] = W[(size_t)(k0+u)*ND + c];
      uint4 o;
      o.x = bfpair(v[0], v[1]); o.y = bfpair(v[2], v[3]);
      o.z = bfpair(v[4], v[5]); o.w = bfpair(v[6], v[7]);
      *((uint4*)(Bt + (size_t)c*ND + k0)) = o;
    }
  }
}

// ---------------- bf16 MFMA GEMM ----------------
// MODE 1: bf16 out to Cb[NN][ND].  MODE 2 (L0): cols<ND -> Cb (h); cols>=ND -> Cb2 (bf16 residual).
template<int K, int MODE>
__global__ __launch_bounds__(256) void k_gemm_bf16(const unsigned short* __restrict__ A,
                                                   const unsigned short* __restrict__ Bt,
                                                   unsigned short* __restrict__ Cb2,
                                                   unsigned short* __restrict__ Cb){
  __shared__ unsigned short As[128*32];
  __shared__ unsigned short Bs[128*32];
  int t = threadIdx.x;
  int lane = t & 63, wid = t >> 6;
  int wm = wid & 1, wn = wid >> 1;
  int r = lane & 15, g = lane >> 4;
  int bm = blockIdx.x * 128;
  int bn = blockIdx.y * 128;
  int srow = t >> 2, scol = (t & 3) * 8;

  int aoff[4], boff[4];
#pragma unroll
  for(int m = 0; m < 4; ++m) aoff[m] = ((wm*64 + m*16 + r) << 5) + (g << 3);
#pragma unroll
  for(int n = 0; n < 4; ++n) boff[n] = ((wn*64 + n*16 + r) << 5) + (g << 3);

  f32x4 acc[4][4] = {};

  for(int k0 = 0; k0 < K; k0 += 32){
    gload16(A + (size_t)(bm + srow)*K      + k0 + scol, (char*)As + t*16);
    gload16(A + (size_t)(bm + 64 + srow)*K + k0 + scol, (char*)As + 4096 + t*16);
    gload16(Bt + (size_t)(bn + srow)*K      + k0 + scol, (char*)Bs + t*16);
    gload16(Bt + (size_t)(bn + 64 + srow)*K + k0 + scol, (char*)Bs + 4096 + t*16);
    __syncthreads();

    bf16x8 af[4], bfv[4];
#pragma unroll
    for(int m = 0; m < 4; ++m) af[m] = *(const bf16x8*)&As[aoff[m]];
#pragma unroll
    for(int n = 0; n < 4; ++n) bfv[n] = *(const bf16x8*)&Bs[boff[n]];
#pragma unroll
    for(int m = 0; m < 4; ++m)
#pragma unroll
      for(int n = 0; n < 4; ++n)
        acc[m][n] = __builtin_amdgcn_mfma_f32_16x16x32_bf16(af[m], bfv[n], acc[m][n], 0, 0, 0);
    __syncthreads();
  }

#pragma unroll
  for(int m = 0; m < 4; ++m){
    int row0 = bm + wm*64 + m*16 + g*4;
#pragma unroll
    for(int n = 0; n < 4; ++n){
      int col = bn + wn*64 + n*16 + r;
#pragma unroll
      for(int i = 0; i < 4; ++i){
        if(row0 + i < NN){
          if(MODE == 1){
            Cb[(size_t)(row0+i)*ND + col] = bf1(acc[m][n][i]);
          } else {
            if(col < ND) Cb[(size_t)(row0+i)*ND + col] = bf1(acc[m][n][i]);
            else         Cb2[(size_t)(row0+i)*ND + (col - ND)] = bf1(acc[m][n][i]);
          }
        }
      }
    }
  }
}

// ---------------- el/er from bf16 h ----------------
__global__ __launch_bounds__(256) void k_elr(const unsigned short* __restrict__ Hm, const float* __restrict__ al,
                                             const float* __restrict__ ar, float* __restrict__ el,
                                             float* __restrict__ er){
  int n = blockIdx.x*4 + (threadIdx.x >> 6);
  int lane = threadIdx.x & 63;
  if(n >= NN) return;
  float4 hv = cvt4(((const ushort4*)(Hm + (size_t)n*ND))[lane]);
  float4 a  = ((const float4*)al)[lane];
  float4 b  = ((const float4*)ar)[lane];
  float sl = hv.x*a.x + hv.y*a.y + hv.z*a.z + hv.w*a.w;
  float sr = hv.x*b.x + hv.y*b.y + hv.z*b.z + hv.w*b.w;
#pragma unroll
  for(int off = 16; off >= 1; off >>= 1){ sl += __shfl_xor(sl, off); sr += __shfl_xor(sr, off); }
  if(lane == 0){ el[n*2+0] = sl; er[n*2+0] = sr; }
  if(lane == 32){ el[n*2+1] = sl; er[n*2+1] = sr; }
}

// ---------------- attention softmax + aggregate (one wave per dst node, 4-deep gather pipeline) ----------------
// bf16 residual in, bf16 out. All __shfl at FULL exec (R5/R6 lesson); select AFTER shuffles.
__global__ __launch_bounds__(256) void k_attn(const unsigned short* __restrict__ Hm, const float* __restrict__ el,
                                              const float* __restrict__ er, const int* __restrict__ rowstart,
                                              const int* __restrict__ srcS, const unsigned short* __restrict__ res,
                                              unsigned short* __restrict__ out){
  int n = blockIdx.x*4 + (threadIdx.x >> 6);
  int lane = threadIdx.x & 63;
  if(n >= NN) return;
  int rs = rowstart[n], re = rowstart[n+1];
  int deg = re - rs;
  float4 acc = cvt4(((const ushort4*)(res + (size_t)n*ND))[lane]);
  if(deg > 0){
    float er0 = er[n*2], er1 = er[n*2+1];
    if(deg <= 64){
      int s = srcS[rs + (lane < deg ? lane : 0)];
      float e0 = -1e30f, e1 = -1e30f;
      if(lane < deg){
        e0 = lrelu(el[s*2]   + er0);
        e1 = lrelu(el[s*2+1] + er1);
      }
      float m0 = e0, m1 = e1;
#pragma unroll
      for(int off = 32; off >= 1; off >>= 1){ m0 = fmaxf(m0, __shfl_xor(m0, off)); m1 = fmaxf(m1, __shfl_xor(m1, off)); }
      float x0 = (lane < deg) ? expf(e0 - m0) : 0.0f;
      float x1 = (lane < deg) ? expf(e1 - m1) : 0.0f;
      float s0 = x0, s1 = x1;
#pragma unroll
      for(int off = 32; off >= 1; off >>= 1){ s0 += __shfl_xor(s0, off); s1 += __shfl_xor(s1, off); }
      x0 *= 1.0f/(s0 + 1e-9f);
      x1 *= 1.0f/(s1 + 1e-9f);
      bool h1 = (lane >= 32);
      for(int j0 = 0; j0 < deg; j0 += 4){
        int sj0 = __shfl(s, j0+0), sj1 = __shfl(s, j0+1);
        int sj2 = __shfl(s, j0+2), sj3 = __shfl(s, j0+3);
        ushort4 g0 = ((const ushort4*)(Hm + (size_t)sj0*ND))[lane];
        ushort4 g1 = ((const ushort4*)(Hm + (size_t)sj1*ND))[lane];
        ushort4 g2 = ((const ushort4*)(Hm + (size_t)sj2*ND))[lane];
        ushort4 g3 = ((const ushort4*)(Hm + (size_t)sj3*ND))[lane];
        float a00 = __shfl(x0, j0+0), a10 = __shfl(x1, j0+0);
        float a01 = __shfl(x0, j0+1), a11 = __shfl(x1, j0+1);
        float a02 = __shfl(x0, j0+2), a12 = __shfl(x1, j0+2);
        float a03 = __shfl(x0, j0+3), a13 = __shfl(x1, j0+3);
        float w0 = h1 ? a10 : a00;
        float w1 = h1 ? a11 : a01;
        float w2 = h1 ? a12 : a02;
        float w3 = h1 ? a13 : a03;
        float4 v0 = cvt4(g0), v1 = cvt4(g1), v2 = cvt4(g2), v3 = cvt4(g3);
        acc.x += w0*v0.x + w1*v1.x + w2*v2.x + w3*v3.x;
        acc.y += w0*v0.y + w1*v1.y + w2*v2.y + w3*v3.y;
        acc.z += w0*v0.z + w1*v1.z + w2*v2.z + w3*v3.z;
        acc.w += w0*v0.w + w1*v1.w + w2*v2.w + w3*v3.w;
      }
    } else {
      float m0 = -1e30f, m1 = -1e30f;
      for(int j = lane; j < deg; j += 64){
        int s = srcS[rs + j];
        m0 = fmaxf(m0, lrelu(el[s*2]   + er0));
        m1 = fmaxf(m1, lrelu(el[s*2+1] + er1));
      }
#pragma unroll
      for(int off = 32; off >= 1; off >>= 1){ m0 = fmaxf(m0, __shfl_xor(m0, off)); m1 = fmaxf(m1, __shfl_xor(m1, off)); }
      float s0 = 0.0f, s1 = 0.0f;
      for(int j = lane; j < deg; j += 64){
        int s = srcS[rs + j];
        s0 += expf(lrelu(el[s*2]   + er0) - m0);
        s1 += expf(lrelu(el[s*2+1] + er1) - m1);
      }
#pragma unroll
      for(int off = 32; off >= 1; off >>= 1){ s0 += __shfl_xor(s0, off); s1 += __shfl_xor(s1, off); }
      float inv = (lane < 32) ? 1.0f/(s0 + 1e-9f) : 1.0f/(s1 + 1e-9f);
      float mh  = (lane < 32) ? m0 : m1;
      for(int j = 0; j < deg; ++j){
        int s = srcS[rs + j];
        float e = (lane < 32) ? lrelu(el[s*2] + er0) : lrelu(el[s*2+1] + er1);
        float a = expf(e - mh) * inv;
        float4 hv = cvt4(((const ushort4*)(Hm + (size_t)s*ND))[lane]);
        acc.x += a*hv.x; acc.y += a*hv.y; acc.z += a*hv.z; acc.w += a*hv.w;
      }
    }
  }
  uint2 pk; pk.x = bfpair(acc.x, acc.y); pk.y = bfpair(acc.z, acc.w);
  ((uint2*)(out + (size_t)n*ND))[lane] = pk;
}

// ---------------- per-graph column stats (bf16 input): coalesced rows + LDS reduce + few atomics ----------------
__global__ __launch_bounds__(256) void k_gstats(const unsigned short* __restrict__ X, const int* __restrict__ gid,
                                                float* __restrict__ gsum, float* __restrict__ gsq){
  __shared__ f32x4 reds[256];
  __shared__ f32x4 redq[256];
  int tid = threadIdx.x;
  int f4 = tid & 63;
  int r  = tid >> 6;
  int n0 = blockIdx.x * 125;
  int g0 = gid[n0];
  f32x4 s0 = {0,0,0,0}, q0 = {0,0,0,0};
  f32x4 s1 = {0,0,0,0}, q1 = {0,0,0,0};
  int cg1 = -1;
  for(int n = n0 + r; n < n0 + 125; n += 4){
    int g = gid[n];
    float4 vv = cvt4(*(const ushort4*)(X + (size_t)n*ND + f4*4));
    f32x4 v = {vv.x, vv.y, vv.z, vv.w};
    if(g == g0){ s0 += v; q0 += v*v; }
    else {
      if(g != cg1){
        if(cg1 >= 0){
#pragma unroll
          for(int j = 0; j < 4; ++j){
            atomicAdd(&gsum[cg1*ND + f4*4 + j], s1[j]);
            atomicAdd(&gsq [cg1*ND + f4*4 + j], q1[j]);
          }
        }
        cg1 = g; s1 = (f32x4){0,0,0,0}; q1 = (f32x4){0,0,0,0};
      }
      s1 += v; q1 += v*v;
    }
  }
  if(cg1 >= 0){
#pragma unroll
    for(int j = 0; j < 4; ++j){
      atomicAdd(&gsum[cg1*ND + f4*4 + j], s1[j]);
      atomicAdd(&gsq [cg1*ND + f4*4 + j], q1[j]);
    }
  }
  reds[tid] = s0; redq[tid] = q0;
  __syncthreads();
  if(r == 0){
    f32x4 ts = reds[f4] + reds[f4+64] + reds[f4+128] + reds[f4+192];
    f32x4 tq = redq[f4] + redq[f4+64] + redq[f4+128] + redq[f4+192];
#pragma unroll
    for(int j = 0; j < 4; ++j){
      atomicAdd(&gsum[g0*ND + f4*4 + j], ts[j]);
      atomicAdd(&gsq [g0*ND + f4*4 + j], tq[j]);
    }
  }
}

// finstats also RESETS gsum/gsq to zero for the next layer
__global__ void k_finstats(float* __restrict__ gsum, float* __restrict__ gsq,
                           const int* __restrict__ cnt, float* __restrict__ gmean, float* __restrict__ grs,
                           float* __restrict__ bnm, float* __restrict__ bnrs){
  int d = threadIdx.x; // 256
  float ts = 0.0f, tq = 0.0f;
  for(int g = 0; g < NG; ++g){
    float c = (float)cnt[g];
    float s = gsum[g*ND + d], q = gsq[g*ND + d];
    gsum[g*ND + d] = 0.0f; gsq[g*ND + d] = 0.0f;
    ts += s; tq += q;
    float m = s / c;
    float v = q / c - m*m;
    gmean[g*ND + d] = m;
    grs[g*ND + d] = rsqrtf(fmaxf(v, 0.0f) + EPSF);
  }
  float bm = ts / (float)NN;
  float bv = tq / (float)NN - bm*bm;
  bnm[d] = bm;
  bnrs[d] = rsqrtf(fmaxf(bv, 0.0f) + EPSF);
}

// ---------------- united norm apply (+ leaky) ----------------
// bf16 X in. LAYER<2: single bf16 out (residual AND next GEMM A, pad rows zeroed).
// LAYER==2: fp32 head_mean out.
template<int LAYER>
__global__ __launch_bounds__(256) void k_norm(const unsigned short* __restrict__ X, const int* __restrict__ gid,
    const float* __restrict__ gmean, const float* __restrict__ grs, const float* __restrict__ bnm,
    const float* __restrict__ bnrs, const float* __restrict__ gamma, const float* __restrict__ beta,
    const float* __restrict__ lbn, const float* __restrict__ lgn, const float* __restrict__ lnn,
    unsigned short* __restrict__ outb, float* __restrict__ outf){
  int n = blockIdx.x*4 + (threadIdx.x >> 6);
  int lane = threadIdx.x & 63;
  if(n >= NPAD) return;
  if(n >= NN){
    if(LAYER < 2){ uint2 z = {0,0}; ((uint2*)(outb + (size_t)n*ND))[lane] = z; }
    return;
  }
  float4 v = cvt4(((const ushort4*)(X + (size_t)n*ND))[lane]);
  float s = v.x + v.y + v.z + v.w;
  float q = v.x*v.x + v.y*v.y + v.z*v.z + v.w*v.w;
#pragma unroll
  for(int off = 32; off >= 1; off >>= 1){ s += __shfl_xor(s, off); q += __shfl_xor(q, off); }
  float nm = s * (1.0f/ND);
  float nv = q * (1.0f/ND) - nm*nm;
  float nrs = rsqrtf(fmaxf(nv, 0.0f) + EPSF);
  int g = gid[n];
  float4 gm = ((const float4*)(gmean + g*ND))[lane];
  float4 gr = ((const float4*)(grs   + g*ND))[lane];
  float4 bm = ((const float4*)bnm)[lane];
  float4 br = ((const float4*)bnrs)[lane];
  float4 ga = ((const float4*)gamma)[lane];
  float4 be = ((const float4*)beta)[lane];
  float4 lb = ((const float4*)lbn)[lane];
  float4 lg = ((const float4*)lgn)[lane];
  float4 ln = ((const float4*)lnn)[lane];
  float4 o;
  o.x = lrelu(ga.x*(lb.x*((v.x-bm.x)*br.x) + lg.x*((v.x-gm.x)*gr.x) + ln.x*((v.x-nm)*nrs)) + be.x);
  o.y = lrelu(ga.y*(lb.y*((v.y-bm.y)*br.y) + lg.y*((v.y-gm.y)*gr.y) + ln.y*((v.y-nm)*nrs)) + be.y);
  o.z = lrelu(ga.z*(lb.z*((v.z-bm.z)*br.z) + lg.z*((v.z-gm.z)*gr.z) + ln.z*((v.z-nm)*nrs)) + be.z);
  o.w = lrelu(ga.w*(lb.w*((v.w-bm.w)*br.w) + lg.w*((v.w-gm.w)*gr.w) + ln.w*((v.w-nm)*nrs)) + be.w);
  if(LAYER < 2){
    uint2 pk; pk.x = bfpair(o.x, o.y); pk.y = bfpair(o.z, o.w);
    ((uint2*)(outb + (size_t)n*ND))[lane] = pk;
  } else {
    float4 p;
    p.x = __shfl_xor(o.x, 32); p.y = __shfl_xor(o.y, 32);
    p.z = __shfl_xor(o.z, 32); p.w = __shfl_xor(o.w, 32);
    if(lane < 32){
      float4 hm;
      hm.x = 0.5f*(o.x + p.x); hm.y = 0.5f*(o.y + p.y);
      hm.z = 0.5f*(o.z + p.z); hm.w = 0.5f*(o.w + p.w);
      ((float4*)(outf + (size_t)n*NC))[lane] = hm;
    }
  }
}

// ---------------- graph readout ----------------
__global__ void k_readout_part(const float* __restrict__ HM, const int* __restrict__ gid,
                               const int* __restrict__ gmn, const int* __restrict__ gmx,
                               float* __restrict__ obuf){
  int g = blockIdx.x >> 3, part = blockIdx.x & 7;
  int c = threadIdx.x; // 128
  int n0 = gmn[g], n1 = gmx[g] + 1;
  int len = n1 - n0;
  int beg = n0 + (int)(((long)len * part) >> 3);
  int end = n0 + (int)(((long)len * (part+1)) >> 3);
  float acc = 0.0f;
  for(int n = beg; n < end; ++n){
    if(gid[n] == g) acc += HM[(size_t)n*NC + c];
  }
  atomicAdd(&obuf[g*NC + c], acc);
}

__global__ void k_readout_fin(const float* __restrict__ obuf, const int* __restrict__ cnt,
                              float* __restrict__ outp){
  int i = blockIdx.x*128 + threadIdx.x; // NG*NC
  int g = i / NC;
  outp[i] = lrelu(obuf[i] / (float)cnt[g]);
}

// ---------------- launch ----------------
extern "C" void kernel_launch(void* const* d_in, const int* in_sizes, int n_in,
                              void* d_out, int out_size, void* d_ws, size_t ws_size,
                              hipStream_t stream){
  const float* X0  = (const float*)d_in[0];
  const int* src   = (const int*)d_in[1];
  const int* dst   = (const int*)d_in[2];
  const int* gid   = (const int*)d_in[3];
  const float* Wm[3] = { (const float*)d_in[4], (const float*)d_in[5], (const float*)d_in[6] };
  const float* resW  = (const float*)d_in[7];
  const float *AL[3], *AR[3], *GA[3], *BE[3], *LB[3], *LG[3], *LN[3];
  for(int i = 0; i < 3; ++i){
    int b = 8 + i*7;
    AL[i] = (const float*)d_in[b];   AR[i] = (const float*)d_in[b+1];
    GA[i] = (const float*)d_in[b+2]; BE[i] = (const float*)d_in[b+3];
    LB[i] = (const float*)d_in[b+4]; LG[i] = (const float*)d_in[b+5]; LN[i] = (const float*)d_in[b+6];
  }
  float* out = (float*)d_out;

  // workspace layout (all node-feature intermediates bf16)
  float* wf = (float*)d_ws;
  unsigned short* Hbf  = (unsigned short*)wf;  wf += (size_t)NN*ND/2;    // h bf16
  unsigned short* XAb  = (unsigned short*)wf;  wf += (size_t)NN*ND/2;    // attn out bf16; L0 A-staging
  unsigned short* XBb  = (unsigned short*)wf;  wf += (size_t)NPAD*ND/2;  // norm out bf16 (residual + GEMM A)
  unsigned short* RESb = (unsigned short*)wf;  wf += (size_t)NN*ND/2;    // L0 residual bf16; later head_mean fp32
  float* el   = wf;                 wf += (size_t)NN*2;
  float* er   = wf;                 wf += (size_t)NN*2;
  float* gsum = wf;                 wf += NG*ND;
  float* gsq  = wf;                 wf += NG*ND;
  float* gmean= wf;                 wf += NG*ND;
  float* grs  = wf;                 wf += NG*ND;
  float* bnm  = wf;                 wf += ND;
  float* bnrs = wf;                 wf += ND;
  float* obuf = wf;                 wf += NG*NC;
  unsigned short* Bt0 = (unsigned short*)wf; wf += (2*ND*NC)/2;   // 512x128 bf16
  unsigned short* Bt1 = (unsigned short*)wf; wf += (ND*ND)/2;     // 256x256 bf16
  unsigned short* Bt2 = (unsigned short*)wf; wf += (ND*ND)/2;     // 256x256 bf16
  int* ip = (int*)wf;
  int* deg      = ip;               ip += NN;
  int* rowstart = ip;               ip += NN + 1;
  int* cur      = ip;               ip += NN;
  int* srcS     = ip;               ip += NE;
  int* cnt      = ip;               ip += NG;
  int* gmn      = ip;               ip += NG;
  int* gmx      = ip;               ip += NG;
  int* bsum     = ip;               ip += SCAN_NB;
  int* boff     = ip;               ip += SCAN_NB;

  unsigned short* A0bf = XAb;            // L0 bf16 A staging (GEMM consumes before attn overwrites)
  float* HMf = (float*)RESb;             // L2 head_mean fp32 (NN*NC floats fit in NN*ND/2 ushort slots)

  // ---- init + prep + CSR + graph meta ----
  k_zero<<<SCAN_NB, 256, 0, stream>>>(deg, cur, cnt, gmn, gmx, gsum, gsq, obuf);
  k_prep<<<2600, 256, 0, stream>>>(X0, Wm[0], resW, Wm[1], Wm[2], (unsigned int*)A0bf, Bt0, Bt1, Bt2);
  k_hist<<<2500, 256, 0, stream>>>(dst, gid, deg, cnt, gmn, gmx);
  k_scan_a<<<SCAN_NB, 256, 0, stream>>>(deg, bsum);
  k_scan_b<<<1, 256, 0, stream>>>(bsum, boff, rowstart);
  k_scan_c<<<SCAN_NB, 256, 0, stream>>>(deg, boff, rowstart);
  k_fill<<<(NE+255)/256, 256, 0, stream>>>(src, dst, rowstart, cur, srcS);

  for(int L = 0; L < 3; ++L){
    if(L == 0){
      dim3 g0(NPAD/128, 4);  // cols 0..255 -> Hbf, 256..511 -> RESb (bf16 residual)
      k_gemm_bf16<NC,2><<<g0, 256, 0, stream>>>(A0bf, Bt0, RESb, Hbf);
    } else {
      dim3 g1(NPAD/128, 2);
      k_gemm_bf16<ND,1><<<g1, 256, 0, stream>>>(XBb, (L == 1) ? Bt1 : Bt2, nullptr, Hbf);
    }
    const unsigned short* resp = (L == 0) ? RESb : XBb;
    k_elr<<<NN/4, 256, 0, stream>>>(Hbf, AL[L], AR[L], el, er);
    k_attn<<<NN/4, 256, 0, stream>>>(Hbf, el, er, rowstart, srcS, resp, XAb);
    k_gstats<<<NN/125, 256, 0, stream>>>(XAb, gid, gsum, gsq);
    k_finstats<<<1, 256, 0, stream>>>(gsum, gsq, cnt, gmean, grs, bnm, bnrs);
    if(L == 0)      k_norm<0><<<NPAD/4, 256, 0, stream>>>(XAb, gid, gmean, grs, bnm, bnrs, GA[0], BE[0], LB[0], LG[0], LN[0], XBb, nullptr);
    else if(L == 1) k_norm<1><<<NPAD/4, 256, 0, stream>>>(XAb, gid, gmean, grs, bnm, bnrs, GA[1], BE[1], LB[1], LG[1], LN[1], XBb, nullptr);
    else            k_norm<2><<<NN/4, 256, 0, stream>>>(XAb, gid, gmean, grs, bnm, bnrs, GA[2], BE[2], LB[2], LG[2], LN[2], nullptr, HMf);
  }
  k_readout_part<<<NG*8, NC, 0, stream>>>(HMf, gid, gmn, gmx, obuf);
  k_readout_fin<<<NG, NC, 0, stream>>>(obuf, cnt, out);
}

// Round 12
// 455.197 us; speedup vs baseline: 1.3814x; 1.0211x over previous
//
#include <hip/hip_runtime.h>
#include <math.h>

#define NN 40000
#define NPAD 40064   // 313 * 128
#define NE 640000
#define NG 40
#define NC 128
#define ND 256
#define SLOPEF 0.2f
#define EPSF 1e-5f
#define SCAN_NB 157  // ceil(40000/256)

typedef short bf16x8 __attribute__((ext_vector_type(8)));
typedef float f32x4 __attribute__((ext_vector_type(4)));

static __device__ __forceinline__ float lrelu(float x){ return x >= 0.0f ? x : SLOPEF * x; }

static __device__ __forceinline__ unsigned int bfpair(float a, float b){
  unsigned int ua = __float_as_uint(a);
  ua = (ua + 0x7fffu + ((ua >> 16) & 1u)) >> 16;
  unsigned int ub = __float_as_uint(b);
  ub = (ub + 0x7fffu + ((ub >> 16) & 1u)) >> 16;
  return ua | (ub << 16);
}
static __device__ __forceinline__ unsigned short bf1(float x){
  unsigned int u = __float_as_uint(x);
  return (unsigned short)((u + 0x7fffu + ((u >> 16) & 1u)) >> 16);
}
static __device__ __forceinline__ float4 cvt4(ushort4 v){
  float4 o;
  o.x = __uint_as_float(((unsigned)v.x) << 16);
  o.y = __uint_as_float(((unsigned)v.y) << 16);
  o.z = __uint_as_float(((unsigned)v.z) << 16);
  o.w = __uint_as_float(((unsigned)v.w) << 16);
  return o;
}

static __device__ __forceinline__ void gload16(const void* gsrc, void* lds){
  __builtin_amdgcn_global_load_lds(
      (const __attribute__((address_space(1))) void*)gsrc,
      (__attribute__((address_space(3))) void*)lds, 16, 0, 0);
}

// ---------------- consolidated zero-init ----------------
__global__ __launch_bounds__(256) void k_zero(int* __restrict__ deg, int* __restrict__ cur,
                                              int* __restrict__ cnt, int* __restrict__ gmn,
                                              int* __restrict__ gmx, float* __restrict__ gsum,
                                              float* __restrict__ gsq, float* __restrict__ obuf){
  int i = blockIdx.x*256 + threadIdx.x;
  int stride = gridDim.x*256;
  for(int j = i; j < NN; j += stride){ deg[j] = 0; cur[j] = 0; }
  for(int j = i; j < NG; j += stride){ cnt[j] = 0; gmn[j] = 0x7f7f7f7f; gmx[j] = -1; }
  for(int j = i; j < NG*ND; j += stride){ gsum[j] = 0.0f; gsq[j] = 0.0f; }
  for(int j = i; j < NG*NC; j += stride){ obuf[j] = 0.0f; }
}

// ---------------- merged histogram: edge degree + graph count/min/max ----------------
__global__ __launch_bounds__(256) void k_hist(const int* __restrict__ dst, const int* __restrict__ gid,
                                              int* __restrict__ deg, int* __restrict__ cnt,
                                              int* __restrict__ gmn, int* __restrict__ gmx){
  __shared__ int lc[NG], lmn[NG], lmx[NG];
  int tid = threadIdx.x;
  for(int i = tid; i < NG; i += 256){ lc[i] = 0; lmn[i] = 0x7f7f7f7f; lmx[i] = -1; }
  __syncthreads();
  int stride = gridDim.x*256;
  int base = blockIdx.x*256 + tid;
  for(int n = base; n < NN; n += stride){
    int g = gid[n];
    atomicAdd(&lc[g], 1);
    atomicMin(&lmn[g], n);
    atomicMax(&lmx[g], n);
  }
  for(int e = base; e < NE; e += stride) atomicAdd(&deg[dst[e]], 1);
  __syncthreads();
  for(int i = tid; i < NG; i += 256){
    if(lc[i] > 0){
      atomicAdd(&cnt[i], lc[i]);
      atomicMin(&gmn[i], lmn[i]);
      atomicMax(&gmx[i], lmx[i]);
    }
  }
}

// -------- multi-block exclusive scan of deg[NN] -> rowstart[NN+1] --------
__global__ __launch_bounds__(256) void k_scan_a(const int* __restrict__ deg, int* __restrict__ bsum){
  int tid = threadIdx.x;
  int i = blockIdx.x*256 + tid;
  int v = (i < NN) ? deg[i] : 0;
#pragma unroll
  for(int off = 32; off >= 1; off >>= 1) v += __shfl_xor(v, off);
  __shared__ int ws[4];
  if((tid & 63) == 0) ws[tid >> 6] = v;
  __syncthreads();
  if(tid == 0) bsum[blockIdx.x] = ws[0] + ws[1] + ws[2] + ws[3];
}

__global__ __launch_bounds__(256) void k_scan_b(int* __restrict__ bsum, int* __restrict__ boff,
                                                int* __restrict__ rowstart){
  __shared__ int lds[256];
  int tid = threadIdx.x;
  int v = (tid < SCAN_NB) ? bsum[tid] : 0;
  lds[tid] = v;
  __syncthreads();
  for(int off = 1; off < 256; off <<= 1){
    int t = (tid >= off) ? lds[tid - off] : 0;
    __syncthreads();
    lds[tid] += t;
    __syncthreads();
  }
  if(tid < SCAN_NB) boff[tid] = lds[tid] - v;  // exclusive
  if(tid == SCAN_NB - 1) rowstart[NN] = lds[tid];
}

__global__ __launch_bounds__(256) void k_scan_c(const int* __restrict__ deg, const int* __restrict__ boff,
                                                int* __restrict__ rowstart){
  __shared__ int lds[256];
  int tid = threadIdx.x;
  int i = blockIdx.x*256 + tid;
  int v = (i < NN) ? deg[i] : 0;
  lds[tid] = v;
  __syncthreads();
  for(int off = 1; off < 256; off <<= 1){
    int t = (tid >= off) ? lds[tid - off] : 0;
    __syncthreads();
    lds[tid] += t;
    __syncthreads();
  }
  if(i < NN) rowstart[i] = boff[blockIdx.x] + lds[tid] - v;
}

__global__ void k_fill(const int* __restrict__ src, const int* __restrict__ dst,
                       const int* __restrict__ rowstart, int* __restrict__ cur, int* __restrict__ srcS){
  int e = blockIdx.x*256 + threadIdx.x;
  if(e < NE){
    int d = dst[e];
    int slot = rowstart[d] + atomicAdd(&cur[d], 1);
    srcS[slot] = src[e];
  }
}

// ---------------- upfront prep: X0->bf16 A, all weight transposes ----------------
#define PREP_A  (NPAD*NC/8)          // 641024
#define PREP_W0 (2*ND*NC/8)          // 8192
#define PREP_W  (ND*ND/8)            // 8192
__global__ __launch_bounds__(256) void k_prep(const float* __restrict__ X0,
                                              const float* __restrict__ W0, const float* __restrict__ Wr,
                                              const float* __restrict__ W1, const float* __restrict__ W2,
                                              unsigned int* __restrict__ A0,
                                              unsigned short* __restrict__ Bt0,
                                              unsigned short* __restrict__ Bt1,
                                              unsigned short* __restrict__ Bt2){
  int total = PREP_A + PREP_W0 + 2*PREP_W;
  for(int i = blockIdx.x*256 + threadIdx.x; i < total; i += gridDim.x*256){
    if(i < PREP_A){
      long e8 = (long)i * 8;
      int row = (int)(e8 / NC);
      int col = (int)(e8 - (long)row * NC);
      uint4 o;
      if(row < NN){
        const float4* p = (const float4*)(X0 + (size_t)row*NC + col);
        float4 v0 = p[0], v1 = p[1];
        o.x = bfpair(v0.x, v0.y); o.y = bfpair(v0.z, v0.w);
        o.z = bfpair(v1.x, v1.y); o.w = bfpair(v1.z, v1.w);
      } else o = make_uint4(0,0,0,0);
      ((uint4*)A0)[i] = o;
    } else if(i < PREP_A + PREP_W0){
      int j = i - PREP_A;
      int c = j >> 4;                 // NC/8 = 16
      int k0 = (j & 15) * 8;
      const float* W = (c < ND) ? W0 : Wr;
      int cc = c & (ND-1);
      float v[8];
#pragma unroll
      for(int u = 0; u < 8; ++u) v[u] = W[(size_t)(k0+u)*ND + cc];
      uint4 o;
      o.x = bfpair(v[0], v[1]); o.y = bfpair(v[2], v[3]);
      o.z = bfpair(v[4], v[5]); o.w = bfpair(v[6], v[7]);
      *((uint4*)(Bt0 + (size_t)c*NC + k0)) = o;
    } else {
      int j = i - PREP_A - PREP_W0;
      const float* W = (j < PREP_W) ? W1 : W2;
      unsigned short* Bt = (j < PREP_W) ? Bt1 : Bt2;
      j &= (PREP_W - 1);
      int c = j >> 5;                 // ND/8 = 32
      int k0 = (j & 31) * 8;
      float v[8];
#pragma unroll
      for(int u = 0; u < 8; ++u) v[u] = W[(size_t)(k0+u)*ND + c];
      uint4 o;
      o.x = bfpair(v[0], v[1]); o.y = bfpair(v[2], v[3]);
      o.z = bfpair(v[4], v[5]); o.w = bfpair(v[6], v[7]);
      *((uint4*)(Bt + (size_t)c*ND + k0)) = o;
    }
  }
}

// ---------------- bf16 MFMA GEMM (+ fused el/er via LDS, atomics-free) ----------------
// MODE 1: bf16 out to Cb[NN][ND].  MODE 2 (L0): cols<ND -> Cb (h); cols>=ND -> Cb2 (bf16 residual).
// Each block's 128-col band lies in ONE head (bn<ND); its el/er contributions are complete,
// reduced in LDS (reusing the staging buffer post-K-loop) and stored without atomics.
template<int K, int MODE>
__global__ __launch_bounds__(256) void k_gemm_bf16(const unsigned short* __restrict__ A,
                                                   const unsigned short* __restrict__ Bt,
                                                   unsigned short* __restrict__ Cb2,
                                                   unsigned short* __restrict__ Cb,
                                                   const float* __restrict__ al,
                                                   const float* __restrict__ ar,
                                                   float* __restrict__ el,
                                                   float* __restrict__ er){
  __shared__ float red[8192];                       // 32 KB; first 16 KB doubles as staging
  unsigned short* As = (unsigned short*)red;        // 128x32 ushort = 8 KB
  unsigned short* Bs = As + 4096;                   // 8 KB
  int t = threadIdx.x;
  int lane = t & 63, wid = t >> 6;
  int wm = wid & 1, wn = wid >> 1;
  int r = lane & 15, g = lane >> 4;
  int bm = blockIdx.x * 128;
  int bn = blockIdx.y * 128;
  int srow = t >> 2, scol = (t & 3) * 8;

  int aoff[4], boff[4];
#pragma unroll
  for(int m = 0; m < 4; ++m) aoff[m] = ((wm*64 + m*16 + r) << 5) + (g << 3);
#pragma unroll
  for(int n = 0; n < 4; ++n) boff[n] = ((wn*64 + n*16 + r) << 5) + (g << 3);

  f32x4 acc[4][4] = {};

  for(int k0 = 0; k0 < K; k0 += 32){
    gload16(A + (size_t)(bm + srow)*K      + k0 + scol, (char*)As + t*16);
    gload16(A + (size_t)(bm + 64 + srow)*K + k0 + scol, (char*)As + 4096 + t*16);
    gload16(Bt + (size_t)(bn + srow)*K      + k0 + scol, (char*)Bs + t*16);
    gload16(Bt + (size_t)(bn + 64 + srow)*K + k0 + scol, (char*)Bs + 4096 + t*16);
    __syncthreads();

    bf16x8 af[4], bfv[4];
#pragma unroll
    for(int m = 0; m < 4; ++m) af[m] = *(const bf16x8*)&As[aoff[m]];
#pragma unroll
    for(int n = 0; n < 4; ++n) bfv[n] = *(const bf16x8*)&Bs[boff[n]];
#pragma unroll
    for(int m = 0; m < 4; ++m)
#pragma unroll
      for(int n = 0; n < 4; ++n)
        acc[m][n] = __builtin_amdgcn_mfma_f32_16x16x32_bf16(af[m], bfv[n], acc[m][n], 0, 0, 0);
    __syncthreads();
  }

  // C write
#pragma unroll
  for(int m = 0; m < 4; ++m){
    int row0 = bm + wm*64 + m*16 + g*4;
#pragma unroll
    for(int n = 0; n < 4; ++n){
      int col = bn + wn*64 + n*16 + r;
#pragma unroll
      for(int i = 0; i < 4; ++i){
        if(row0 + i < NN){
          if(MODE == 1){
            Cb[(size_t)(row0+i)*ND + col] = bf1(acc[m][n][i]);
          } else {
            if(col < ND) Cb[(size_t)(row0+i)*ND + col] = bf1(acc[m][n][i]);
            else         Cb2[(size_t)(row0+i)*ND + (col - ND)] = bf1(acc[m][n][i]);
          }
        }
      }
    }
  }

  // fused el/er (h-columns only; block-uniform condition so the syncthreads are safe)
  if(MODE == 1 || bn < ND){
    int head = (bn >= NC) ? 1 : 0;
    float alv[4], arv[4];
#pragma unroll
    for(int n = 0; n < 4; ++n){
      int col = bn + wn*64 + n*16 + r;
      alv[n] = al[col]; arv[n] = ar[col];
    }
    // per-thread 4-col partials into LDS: red[row*32 + wn*16 + r] (el), +4096 (er)
#pragma unroll
    for(int m = 0; m < 4; ++m){
#pragma unroll
      for(int i = 0; i < 4; ++i){
        int row = wm*64 + m*16 + g*4 + i;   // 0..127 (local)
        float pel = acc[m][0][i]*alv[0] + acc[m][1][i]*alv[1] + acc[m][2][i]*alv[2] + acc[m][3][i]*alv[3];
        float per = acc[m][0][i]*arv[0] + acc[m][1][i]*arv[1] + acc[m][2][i]*arv[2] + acc[m][3][i]*arv[3];
        red[row*32 + wn*16 + r]        = pel;
        red[4096 + row*32 + wn*16 + r] = per;
      }
    }
    __syncthreads();
    // 256 threads: tid<128 sums el for row=tid; tid>=128 sums er for row=tid-128.
    // rotated LDS reads avoid the all-lanes-same-bank conflict.
    int row = t & 127;
    int base = (t < 128) ? 0 : 4096;
    float s = 0.0f;
#pragma unroll
    for(int j = 0; j < 32; ++j) s += red[base + row*32 + ((j + t) & 31)];
    int grow = bm + row;
    if(grow < NN){
      if(t < 128) el[(size_t)grow*2 + head] = s;
      else        er[(size_t)grow*2 + head] = s;
    }
  }
}

// ---------------- attention softmax + aggregate (one wave per dst node, 4-deep gather pipeline) ----------------
// bf16 residual in, bf16 out. All __shfl at FULL exec (R5/R6 lesson); select AFTER shuffles.
__global__ __launch_bounds__(256) void k_attn(const unsigned short* __restrict__ Hm, const float* __restrict__ el,
                                              const float* __restrict__ er, const int* __restrict__ rowstart,
                                              const int* __restrict__ srcS, const unsigned short* __restrict__ res,
                                              unsigned short* __restrict__ out){
  int n = blockIdx.x*4 + (threadIdx.x >> 6);
  int lane = threadIdx.x & 63;
  if(n >= NN) return;
  int rs = rowstart[n], re = rowstart[n+1];
  int deg = re - rs;
  float4 acc = cvt4(((const ushort4*)(res + (size_t)n*ND))[lane]);
  if(deg > 0){
    float er0 = er[n*2], er1 = er[n*2+1];
    if(deg <= 64){
      int s = srcS[rs + (lane < deg ? lane : 0)];
      float e0 = -1e30f, e1 = -1e30f;
      if(lane < deg){
        e0 = lrelu(el[s*2]   + er0);
        e1 = lrelu(el[s*2+1] + er1);
      }
      float m0 = e0, m1 = e1;
#pragma unroll
      for(int off = 32; off >= 1; off >>= 1){ m0 = fmaxf(m0, __shfl_xor(m0, off)); m1 = fmaxf(m1, __shfl_xor(m1, off)); }
      float x0 = (lane < deg) ? expf(e0 - m0) : 0.0f;
      float x1 = (lane < deg) ? expf(e1 - m1) : 0.0f;
      float s0 = x0, s1 = x1;
#pragma unroll
      for(int off = 32; off >= 1; off >>= 1){ s0 += __shfl_xor(s0, off); s1 += __shfl_xor(s1, off); }
      x0 *= 1.0f/(s0 + 1e-9f);
      x1 *= 1.0f/(s1 + 1e-9f);
      bool h1 = (lane >= 32);
      for(int j0 = 0; j0 < deg; j0 += 4){
        int sj0 = __shfl(s, j0+0), sj1 = __shfl(s, j0+1);
        int sj2 = __shfl(s, j0+2), sj3 = __shfl(s, j0+3);
        ushort4 g0 = ((const ushort4*)(Hm + (size_t)sj0*ND))[lane];
        ushort4 g1 = ((const ushort4*)(Hm + (size_t)sj1*ND))[lane];
        ushort4 g2 = ((const ushort4*)(Hm + (size_t)sj2*ND))[lane];
        ushort4 g3 = ((const ushort4*)(Hm + (size_t)sj3*ND))[lane];
        float a00 = __shfl(x0, j0+0), a10 = __shfl(x1, j0+0);
        float a01 = __shfl(x0, j0+1), a11 = __shfl(x1, j0+1);
        float a02 = __shfl(x0, j0+2), a12 = __shfl(x1, j0+2);
        float a03 = __shfl(x0, j0+3), a13 = __shfl(x1, j0+3);
        float w0 = h1 ? a10 : a00;
        float w1 = h1 ? a11 : a01;
        float w2 = h1 ? a12 : a02;
        float w3 = h1 ? a13 : a03;
        float4 v0 = cvt4(g0), v1 = cvt4(g1), v2 = cvt4(g2), v3 = cvt4(g3);
        acc.x += w0*v0.x + w1*v1.x + w2*v2.x + w3*v3.x;
        acc.y += w0*v0.y + w1*v1.y + w2*v2.y + w3*v3.y;
        acc.z += w0*v0.z + w1*v1.z + w2*v2.z + w3*v3.z;
        acc.w += w0*v0.w + w1*v1.w + w2*v2.w + w3*v3.w;
      }
    } else {
      float m0 = -1e30f, m1 = -1e30f;
      for(int j = lane; j < deg; j += 64){
        int s = srcS[rs + j];
        m0 = fmaxf(m0, lrelu(el[s*2]   + er0));
        m1 = fmaxf(m1, lrelu(el[s*2+1] + er1));
      }
#pragma unroll
      for(int off = 32; off >= 1; off >>= 1){ m0 = fmaxf(m0, __shfl_xor(m0, off)); m1 = fmaxf(m1, __shfl_xor(m1, off)); }
      float s0 = 0.0f, s1 = 0.0f;
      for(int j = lane; j < deg; j += 64){
        int s = srcS[rs + j];
        s0 += expf(lrelu(el[s*2]   + er0) - m0);
        s1 += expf(lrelu(el[s*2+1] + er1) - m1);
      }
#pragma unroll
      for(int off = 32; off >= 1; off >>= 1){ s0 += __shfl_xor(s0, off); s1 += __shfl_xor(s1, off); }
      float inv = (lane < 32) ? 1.0f/(s0 + 1e-9f) : 1.0f/(s1 + 1e-9f);
      float mh  = (lane < 32) ? m0 : m1;
      for(int j = 0; j < deg; ++j){
        int s = srcS[rs + j];
        float e = (lane < 32) ? lrelu(el[s*2] + er0) : lrelu(el[s*2+1] + er1);
        float a = expf(e - mh) * inv;
        float4 hv = cvt4(((const ushort4*)(Hm + (size_t)s*ND))[lane]);
        acc.x += a*hv.x; acc.y += a*hv.y; acc.z += a*hv.z; acc.w += a*hv.w;
      }
    }
  }
  uint2 pk; pk.x = bfpair(acc.x, acc.y); pk.y = bfpair(acc.z, acc.w);
  ((uint2*)(out + (size_t)n*ND))[lane] = pk;
}

// ---------------- per-graph column stats (bf16 input): coalesced rows + LDS reduce + few atomics ----------------
__global__ __launch_bounds__(256) void k_gstats(const unsigned short* __restrict__ X, const int* __restrict__ gid,
                                                float* __restrict__ gsum, float* __restrict__ gsq){
  __shared__ f32x4 reds[256];
  __shared__ f32x4 redq[256];
  int tid = threadIdx.x;
  int f4 = tid & 63;
  int r  = tid >> 6;
  int n0 = blockIdx.x * 125;
  int g0 = gid[n0];
  f32x4 s0 = {0,0,0,0}, q0 = {0,0,0,0};
  f32x4 s1 = {0,0,0,0}, q1 = {0,0,0,0};
  int cg1 = -1;
  for(int n = n0 + r; n < n0 + 125; n += 4){
    int g = gid[n];
    float4 vv = cvt4(*(const ushort4*)(X + (size_t)n*ND + f4*4));
    f32x4 v = {vv.x, vv.y, vv.z, vv.w};
    if(g == g0){ s0 += v; q0 += v*v; }
    else {
      if(g != cg1){
        if(cg1 >= 0){
#pragma unroll
          for(int j = 0; j < 4; ++j){
            atomicAdd(&gsum[cg1*ND + f4*4 + j], s1[j]);
            atomicAdd(&gsq [cg1*ND + f4*4 + j], q1[j]);
          }
        }
        cg1 = g; s1 = (f32x4){0,0,0,0}; q1 = (f32x4){0,0,0,0};
      }
      s1 += v; q1 += v*v;
    }
  }
  if(cg1 >= 0){
#pragma unroll
    for(int j = 0; j < 4; ++j){
      atomicAdd(&gsum[cg1*ND + f4*4 + j], s1[j]);
      atomicAdd(&gsq [cg1*ND + f4*4 + j], q1[j]);
    }
  }
  reds[tid] = s0; redq[tid] = q0;
  __syncthreads();
  if(r == 0){
    f32x4 ts = reds[f4] + reds[f4+64] + reds[f4+128] + reds[f4+192];
    f32x4 tq = redq[f4] + redq[f4+64] + redq[f4+128] + redq[f4+192];
#pragma unroll
    for(int j = 0; j < 4; ++j){
      atomicAdd(&gsum[g0*ND + f4*4 + j], ts[j]);
      atomicAdd(&gsq [g0*ND + f4*4 + j], tq[j]);
    }
  }
}

// finstats also RESETS gsum/gsq to zero for the next layer
__global__ void k_finstats(float* __restrict__ gsum, float* __restrict__ gsq,
                           const int* __restrict__ cnt, float* __restrict__ gmean, float* __restrict__ grs,
                           float* __restrict__ bnm, float* __restrict__ bnrs){
  int d = threadIdx.x; // 256
  float ts = 0.0f, tq = 0.0f;
  for(int g = 0; g < NG; ++g){
    float c = (float)cnt[g];
    float s = gsum[g*ND + d], q = gsq[g*ND + d];
    gsum[g*ND + d] = 0.0f; gsq[g*ND + d] = 0.0f;
    ts += s; tq += q;
    float m = s / c;
    float v = q / c - m*m;
    gmean[g*ND + d] = m;
    grs[g*ND + d] = rsqrtf(fmaxf(v, 0.0f) + EPSF);
  }
  float bm = ts / (float)NN;
  float bv = tq / (float)NN - bm*bm;
  bnm[d] = bm;
  bnrs[d] = rsqrtf(fmaxf(bv, 0.0f) + EPSF);
}

// ---------------- united norm apply (+ leaky) ----------------
// bf16 X in. LAYER<2: single bf16 out (residual AND next GEMM A, pad rows zeroed).
// LAYER==2: fp32 head_mean out.
template<int LAYER>
__global__ __launch_bounds__(256) void k_norm(const unsigned short* __restrict__ X, const int* __restrict__ gid,
    const float* __restrict__ gmean, const float* __restrict__ grs, const float* __restrict__ bnm,
    const float* __restrict__ bnrs, const float* __restrict__ gamma, const float* __restrict__ beta,
    const float* __restrict__ lbn, const float* __restrict__ lgn, const float* __restrict__ lnn,
    unsigned short* __restrict__ outb, float* __restrict__ outf){
  int n = blockIdx.x*4 + (threadIdx.x >> 6);
  int lane = threadIdx.x & 63;
  if(n >= NPAD) return;
  if(n >= NN){
    if(LAYER < 2){ uint2 z = {0,0}; ((uint2*)(outb + (size_t)n*ND))[lane] = z; }
    return;
  }
  float4 v = cvt4(((const ushort4*)(X + (size_t)n*ND))[lane]);
  float s = v.x + v.y + v.z + v.w;
  float q = v.x*v.x + v.y*v.y + v.z*v.z + v.w*v.w;
#pragma unroll
  for(int off = 32; off >= 1; off >>= 1){ s += __shfl_xor(s, off); q += __shfl_xor(q, off); }
  float nm = s * (1.0f/ND);
  float nv = q * (1.0f/ND) - nm*nm;
  float nrs = rsqrtf(fmaxf(nv, 0.0f) + EPSF);
  int g = gid[n];
  float4 gm = ((const float4*)(gmean + g*ND))[lane];
  float4 gr = ((const float4*)(grs   + g*ND))[lane];
  float4 bm = ((const float4*)bnm)[lane];
  float4 br = ((const float4*)bnrs)[lane];
  float4 ga = ((const float4*)gamma)[lane];
  float4 be = ((const float4*)beta)[lane];
  float4 lb = ((const float4*)lbn)[lane];
  float4 lg = ((const float4*)lgn)[lane];
  float4 ln = ((const float4*)lnn)[lane];
  float4 o;
  o.x = lrelu(ga.x*(lb.x*((v.x-bm.x)*br.x) + lg.x*((v.x-gm.x)*gr.x) + ln.x*((v.x-nm)*nrs)) + be.x);
  o.y = lrelu(ga.y*(lb.y*((v.y-bm.y)*br.y) + lg.y*((v.y-gm.y)*gr.y) + ln.y*((v.y-nm)*nrs)) + be.y);
  o.z = lrelu(ga.z*(lb.z*((v.z-bm.z)*br.z) + lg.z*((v.z-gm.z)*gr.z) + ln.z*((v.z-nm)*nrs)) + be.z);
  o.w = lrelu(ga.w*(lb.w*((v.w-bm.w)*br.w) + lg.w*((v.w-gm.w)*gr.w) + ln.w*((v.w-nm)*nrs)) + be.w);
  if(LAYER < 2){
    uint2 pk; pk.x = bfpair(o.x, o.y); pk.y = bfpair(o.z, o.w);
    ((uint2*)(outb + (size_t)n*ND))[lane] = pk;
  } else {
    float4 p;
    p.x = __shfl_xor(o.x, 32); p.y = __shfl_xor(o.y, 32);
    p.z = __shfl_xor(o.z, 32); p.w = __shfl_xor(o.w, 32);
    if(lane < 32){
      float4 hm;
      hm.x = 0.5f*(o.x + p.x); hm.y = 0.5f*(o.y + p.y);
      hm.z = 0.5f*(o.z + p.z); hm.w = 0.5f*(o.w + p.w);
      ((float4*)(outf + (size_t)n*NC))[lane] = hm;
    }
  }
}

// ---------------- graph readout ----------------
__global__ void k_readout_part(const float* __restrict__ HM, const int* __restrict__ gid,
                               const int* __restrict__ gmn, const int* __restrict__ gmx,
                               float* __restrict__ obuf){
  int g = blockIdx.x >> 3, part = blockIdx.x & 7;
  int c = threadIdx.x; // 128
  int n0 = gmn[g], n1 = gmx[g] + 1;
  int len = n1 - n0;
  int beg = n0 + (int)(((long)len * part) >> 3);
  int end = n0 + (int)(((long)len * (part+1)) >> 3);
  float acc = 0.0f;
  for(int n = beg; n < end; ++n){
    if(gid[n] == g) acc += HM[(size_t)n*NC + c];
  }
  atomicAdd(&obuf[g*NC + c], acc);
}

__global__ void k_readout_fin(const float* __restrict__ obuf, const int* __restrict__ cnt,
                              float* __restrict__ outp){
  int i = blockIdx.x*128 + threadIdx.x; // NG*NC
  int g = i / NC;
  outp[i] = lrelu(obuf[i] / (float)cnt[g]);
}

// ---------------- launch ----------------
extern "C" void kernel_launch(void* const* d_in, const int* in_sizes, int n_in,
                              void* d_out, int out_size, void* d_ws, size_t ws_size,
                              hipStream_t stream){
  const float* X0  = (const float*)d_in[0];
  const int* src   = (const int*)d_in[1];
  const int* dst   = (const int*)d_in[2];
  const int* gid   = (const int*)d_in[3];
  const float* Wm[3] = { (const float*)d_in[4], (const float*)d_in[5], (const float*)d_in[6] };
  const float* resW  = (const float*)d_in[7];
  const float *AL[3], *AR[3], *GA[3], *BE[3], *LB[3], *LG[3], *LN[3];
  for(int i = 0; i < 3; ++i){
    int b = 8 + i*7;
    AL[i] = (const float*)d_in[b];   AR[i] = (const float*)d_in[b+1];
    GA[i] = (const float*)d_in[b+2]; BE[i] = (const float*)d_in[b+3];
    LB[i] = (const float*)d_in[b+4]; LG[i] = (const float*)d_in[b+5]; LN[i] = (const float*)d_in[b+6];
  }
  float* out = (float*)d_out;

  // workspace layout (all node-feature intermediates bf16)
  float* wf = (float*)d_ws;
  unsigned short* Hbf  = (unsigned short*)wf;  wf += (size_t)NN*ND/2;    // h bf16
  unsigned short* XAb  = (unsigned short*)wf;  wf += (size_t)NN*ND/2;    // attn out bf16; L0 A-staging
  unsigned short* XBb  = (unsigned short*)wf;  wf += (size_t)NPAD*ND/2;  // norm out bf16 (residual + GEMM A)
  unsigned short* RESb = (unsigned short*)wf;  wf += (size_t)NN*ND/2;    // L0 residual bf16; later head_mean fp32
  float* el   = wf;                 wf += (size_t)NN*2;
  float* er   = wf;                 wf += (size_t)NN*2;
  float* gsum = wf;                 wf += NG*ND;
  float* gsq  = wf;                 wf += NG*ND;
  float* gmean= wf;                 wf += NG*ND;
  float* grs  = wf;                 wf += NG*ND;
  float* bnm  = wf;                 wf += ND;
  float* bnrs = wf;                 wf += ND;
  float* obuf = wf;                 wf += NG*NC;
  unsigned short* Bt0 = (unsigned short*)wf; wf += (2*ND*NC)/2;   // 512x128 bf16
  unsigned short* Bt1 = (unsigned short*)wf; wf += (ND*ND)/2;     // 256x256 bf16
  unsigned short* Bt2 = (unsigned short*)wf; wf += (ND*ND)/2;     // 256x256 bf16
  int* ip = (int*)wf;
  int* deg      = ip;               ip += NN;
  int* rowstart = ip;               ip += NN + 1;
  int* cur      = ip;               ip += NN;
  int* srcS     = ip;               ip += NE;
  int* cnt      = ip;               ip += NG;
  int* gmn      = ip;               ip += NG;
  int* gmx      = ip;               ip += NG;
  int* bsum     = ip;               ip += SCAN_NB;
  int* boff     = ip;               ip += SCAN_NB;

  unsigned short* A0bf = XAb;            // L0 bf16 A staging (GEMM consumes before attn overwrites)
  float* HMf = (float*)RESb;             // L2 head_mean fp32 (NN*NC floats fit in NN*ND/2 ushort slots)

  // ---- init + prep + CSR + graph meta ----
  k_zero<<<SCAN_NB, 256, 0, stream>>>(deg, cur, cnt, gmn, gmx, gsum, gsq, obuf);
  k_prep<<<2600, 256, 0, stream>>>(X0, Wm[0], resW, Wm[1], Wm[2], (unsigned int*)A0bf, Bt0, Bt1, Bt2);
  k_hist<<<2500, 256, 0, stream>>>(dst, gid, deg, cnt, gmn, gmx);
  k_scan_a<<<SCAN_NB, 256, 0, stream>>>(deg, bsum);
  k_scan_b<<<1, 256, 0, stream>>>(bsum, boff, rowstart);
  k_scan_c<<<SCAN_NB, 256, 0, stream>>>(deg, boff, rowstart);
  k_fill<<<(NE+255)/256, 256, 0, stream>>>(src, dst, rowstart, cur, srcS);

  for(int L = 0; L < 3; ++L){
    if(L == 0){
      dim3 g0(NPAD/128, 4);  // cols 0..255 -> Hbf, 256..511 -> RESb (bf16 residual)
      k_gemm_bf16<NC,2><<<g0, 256, 0, stream>>>(A0bf, Bt0, RESb, Hbf, AL[0], AR[0], el, er);
    } else {
      dim3 g1(NPAD/128, 2);
      k_gemm_bf16<ND,1><<<g1, 256, 0, stream>>>(XBb, (L == 1) ? Bt1 : Bt2, nullptr, Hbf, AL[L], AR[L], el, er);
    }
    const unsigned short* resp = (L == 0) ? RESb : XBb;
    k_attn<<<NN/4, 256, 0, stream>>>(Hbf, el, er, rowstart, srcS, resp, XAb);
    k_gstats<<<NN/125, 256, 0, stream>>>(XAb, gid, gsum, gsq);
    k_finstats<<<1, 256, 0, stream>>>(gsum, gsq, cnt, gmean, grs, bnm, bnrs);
    if(L == 0)      k_norm<0><<<NPAD/4, 256, 0, stream>>>(XAb, gid, gmean, grs, bnm, bnrs, GA[0], BE[0], LB[0], LG[0], LN[0], XBb, nullptr);
    else if(L == 1) k_norm<1><<<NPAD/4, 256, 0, stream>>>(XAb, gid, gmean, grs, bnm, bnrs, GA[1], BE[1], LB[1], LG[1], LN[1], XBb, nullptr);
    else            k_norm<2><<<NN/4, 256, 0, stream>>>(XAb, gid, gmean, grs, bnm, bnrs, GA[2], BE[2], LB[2], LG[2], LN[2], nullptr, HMf);
  }
  k_readout_part<<<NG*8, NC, 0, stream>>>(HMf, gid, gmn, gmx, obuf);
  k_readout_fin<<<NG, NC, 0, stream>>>(obuf, cnt, out);
}

// Round 13
// 434.850 us; speedup vs baseline: 1.4461x; 1.0468x over previous
//
#include <hip/hip_runtime.h>
#include <math.h>

#define NN 40000
#define NPAD 40064   // 313 * 128
#define NE 640000
#define NG 40
#define NC 128
#define ND 256
#define SLOPEF 0.2f
#define EPSF 1e-5f
#define SCAN_NB 157  // ceil(40000/256)

typedef short bf16x8 __attribute__((ext_vector_type(8)));
typedef float f32x4 __attribute__((ext_vector_type(4)));

static __device__ __forceinline__ float lrelu(float x){ return x >= 0.0f ? x : SLOPEF * x; }

static __device__ __forceinline__ unsigned int bfpair(float a, float b){
  unsigned int ua = __float_as_uint(a);
  ua = (ua + 0x7fffu + ((ua >> 16) & 1u)) >> 16;
  unsigned int ub = __float_as_uint(b);
  ub = (ub + 0x7fffu + ((ub >> 16) & 1u)) >> 16;
  return ua | (ub << 16);
}
static __device__ __forceinline__ unsigned short bf1(float x){
  unsigned int u = __float_as_uint(x);
  return (unsigned short)((u + 0x7fffu + ((u >> 16) & 1u)) >> 16);
}
static __device__ __forceinline__ float4 cvt4(ushort4 v){
  float4 o;
  o.x = __uint_as_float(((unsigned)v.x) << 16);
  o.y = __uint_as_float(((unsigned)v.y) << 16);
  o.z = __uint_as_float(((unsigned)v.z) << 16);
  o.w = __uint_as_float(((unsigned)v.w) << 16);
  return o;
}

static __device__ __forceinline__ void gload16(const void* gsrc, void* lds){
  __builtin_amdgcn_global_load_lds(
      (const __attribute__((address_space(1))) void*)gsrc,
      (__attribute__((address_space(3))) void*)lds, 16, 0, 0);
}

// ---------------- merged histogram: edge degree + graph count/min/max ----------------
__global__ __launch_bounds__(256) void k_hist(const int* __restrict__ dst, const int* __restrict__ gid,
                                              int* __restrict__ deg, int* __restrict__ cnt,
                                              int* __restrict__ gmn, int* __restrict__ gmx){
  __shared__ int lc[NG], lmn[NG], lmx[NG];
  int tid = threadIdx.x;
  for(int i = tid; i < NG; i += 256){ lc[i] = 0; lmn[i] = 0x7f7f7f7f; lmx[i] = -1; }
  __syncthreads();
  int stride = gridDim.x*256;
  int base = blockIdx.x*256 + tid;
  for(int n = base; n < NN; n += stride){
    int g = gid[n];
    atomicAdd(&lc[g], 1);
    atomicMin(&lmn[g], n);
    atomicMax(&lmx[g], n);
  }
  for(int e = base; e < NE; e += stride) atomicAdd(&deg[dst[e]], 1);
  __syncthreads();
  for(int i = tid; i < NG; i += 256){
    if(lc[i] > 0){
      atomicAdd(&cnt[i], lc[i]);
      atomicMin(&gmn[i], lmn[i]);
      atomicMax(&gmx[i], lmx[i]);
    }
  }
}

// -------- multi-block exclusive scan of deg[NN] -> rowstart[NN+1] --------
__global__ __launch_bounds__(256) void k_scan_a(const int* __restrict__ deg, int* __restrict__ bsum){
  int tid = threadIdx.x;
  int i = blockIdx.x*256 + tid;
  int v = (i < NN) ? deg[i] : 0;
#pragma unroll
  for(int off = 32; off >= 1; off >>= 1) v += __shfl_xor(v, off);
  __shared__ int ws[4];
  if((tid & 63) == 0) ws[tid >> 6] = v;
  __syncthreads();
  if(tid == 0) bsum[blockIdx.x] = ws[0] + ws[1] + ws[2] + ws[3];
}

__global__ __launch_bounds__(256) void k_scan_b(int* __restrict__ bsum, int* __restrict__ boff,
                                                int* __restrict__ rowstart){
  __shared__ int lds[256];
  int tid = threadIdx.x;
  int v = (tid < SCAN_NB) ? bsum[tid] : 0;
  lds[tid] = v;
  __syncthreads();
  for(int off = 1; off < 256; off <<= 1){
    int t = (tid >= off) ? lds[tid - off] : 0;
    __syncthreads();
    lds[tid] += t;
    __syncthreads();
  }
  if(tid < SCAN_NB) boff[tid] = lds[tid] - v;  // exclusive
  if(tid == SCAN_NB - 1) rowstart[NN] = lds[tid];
}

__global__ __launch_bounds__(256) void k_scan_c(const int* __restrict__ deg, const int* __restrict__ boff,
                                                int* __restrict__ rowstart){
  __shared__ int lds[256];
  int tid = threadIdx.x;
  int i = blockIdx.x*256 + tid;
  int v = (i < NN) ? deg[i] : 0;
  lds[tid] = v;
  __syncthreads();
  for(int off = 1; off < 256; off <<= 1){
    int t = (tid >= off) ? lds[tid - off] : 0;
    __syncthreads();
    lds[tid] += t;
    __syncthreads();
  }
  if(i < NN) rowstart[i] = boff[blockIdx.x] + lds[tid] - v;
}

__global__ void k_fill(const int* __restrict__ src, const int* __restrict__ dst,
                       const int* __restrict__ rowstart, int* __restrict__ cur, int* __restrict__ srcS){
  int e = blockIdx.x*256 + threadIdx.x;
  if(e < NE){
    int d = dst[e];
    int slot = rowstart[d] + atomicAdd(&cur[d], 1);
    srcS[slot] = src[e];
  }
}

// ---------------- upfront prep: zero-init + X0->bf16 A + all weight transposes ----------------
#define PREP_A  (NPAD*NC/8)          // 641024
#define PREP_W0 (2*ND*NC/8)          // 8192
#define PREP_W  (ND*ND/8)            // 8192
__global__ __launch_bounds__(256) void k_prep(const float* __restrict__ X0,
                                              const float* __restrict__ W0, const float* __restrict__ Wr,
                                              const float* __restrict__ W1, const float* __restrict__ W2,
                                              unsigned int* __restrict__ A0,
                                              unsigned short* __restrict__ Bt0,
                                              unsigned short* __restrict__ Bt1,
                                              unsigned short* __restrict__ Bt2,
                                              int* __restrict__ deg, int* __restrict__ cur,
                                              int* __restrict__ cnt, int* __restrict__ gmn,
                                              int* __restrict__ gmx, float* __restrict__ gsum,
                                              float* __restrict__ gsq, float* __restrict__ obuf){
  int i0 = blockIdx.x*256 + threadIdx.x;
  int stride = gridDim.x*256;
  // zero-init (k_hist and per-layer accumulators depend on this; stream-ordered before them)
  for(int j = i0; j < NN; j += stride){ deg[j] = 0; cur[j] = 0; }
  for(int j = i0; j < NG; j += stride){ cnt[j] = 0; gmn[j] = 0x7f7f7f7f; gmx[j] = -1; }
  for(int j = i0; j < 3*NG*ND; j += stride){ gsum[j] = 0.0f; gsq[j] = 0.0f; }
  for(int j = i0; j < NG*NC; j += stride){ obuf[j] = 0.0f; }
  // convert/transpose work
  int total = PREP_A + PREP_W0 + 2*PREP_W;
  for(int i = i0; i < total; i += stride){
    if(i < PREP_A){
      long e8 = (long)i * 8;
      int row = (int)(e8 / NC);
      int col = (int)(e8 - (long)row * NC);
      uint4 o;
      if(row < NN){
        const float4* p = (const float4*)(X0 + (size_t)row*NC + col);
        float4 v0 = p[0], v1 = p[1];
        o.x = bfpair(v0.x, v0.y); o.y = bfpair(v0.z, v0.w);
        o.z = bfpair(v1.x, v1.y); o.w = bfpair(v1.z, v1.w);
      } else o = make_uint4(0,0,0,0);
      ((uint4*)A0)[i] = o;
    } else if(i < PREP_A + PREP_W0){
      int j = i - PREP_A;
      int c = j >> 4;                 // NC/8 = 16
      int k0 = (j & 15) * 8;
      const float* W = (c < ND) ? W0 : Wr;
      int cc = c & (ND-1);
      float v[8];
#pragma unroll
      for(int u = 0; u < 8; ++u) v[u] = W[(size_t)(k0+u)*ND + cc];
      uint4 o;
      o.x = bfpair(v[0], v[1]); o.y = bfpair(v[2], v[3]);
      o.z = bfpair(v[4], v[5]); o.w = bfpair(v[6], v[7]);
      *((uint4*)(Bt0 + (size_t)c*NC + k0)) = o;
    } else {
      int j = i - PREP_A - PREP_W0;
      const float* W = (j < PREP_W) ? W1 : W2;
      unsigned short* Bt = (j < PREP_W) ? Bt1 : Bt2;
      j &= (PREP_W - 1);
      int c = j >> 5;                 // ND/8 = 32
      int k0 = (j & 31) * 8;
      float v[8];
#pragma unroll
      for(int u = 0; u < 8; ++u) v[u] = W[(size_t)(k0+u)*ND + c];
      uint4 o;
      o.x = bfpair(v[0], v[1]); o.y = bfpair(v[2], v[3]);
      o.z = bfpair(v[4], v[5]); o.w = bfpair(v[6], v[7]);
      *((uint4*)(Bt + (size_t)c*ND + k0)) = o;
    }
  }
}

// ---------------- bf16 MFMA GEMM (+ fused el/er via LDS, atomics-free) ----------------
// MODE 1: bf16 out to Cb[NN][ND].  MODE 2 (L0): cols<ND -> Cb (h); cols>=ND -> Cb2 (bf16 residual).
template<int K, int MODE>
__global__ __launch_bounds__(256) void k_gemm_bf16(const unsigned short* __restrict__ A,
                                                   const unsigned short* __restrict__ Bt,
                                                   unsigned short* __restrict__ Cb2,
                                                   unsigned short* __restrict__ Cb,
                                                   const float* __restrict__ al,
                                                   const float* __restrict__ ar,
                                                   float* __restrict__ el,
                                                   float* __restrict__ er){
  __shared__ float red[8192];                       // 32 KB; first 16 KB doubles as staging
  unsigned short* As = (unsigned short*)red;        // 128x32 ushort = 8 KB
  unsigned short* Bs = As + 4096;                   // 8 KB
  int t = threadIdx.x;
  int lane = t & 63, wid = t >> 6;
  int wm = wid & 1, wn = wid >> 1;
  int r = lane & 15, g = lane >> 4;
  int bm = blockIdx.x * 128;
  int bn = blockIdx.y * 128;
  int srow = t >> 2, scol = (t & 3) * 8;

  int aoff[4], boff[4];
#pragma unroll
  for(int m = 0; m < 4; ++m) aoff[m] = ((wm*64 + m*16 + r) << 5) + (g << 3);
#pragma unroll
  for(int n = 0; n < 4; ++n) boff[n] = ((wn*64 + n*16 + r) << 5) + (g << 3);

  f32x4 acc[4][4] = {};

  for(int k0 = 0; k0 < K; k0 += 32){
    gload16(A + (size_t)(bm + srow)*K      + k0 + scol, (char*)As + t*16);
    gload16(A + (size_t)(bm + 64 + srow)*K + k0 + scol, (char*)As + 4096 + t*16);
    gload16(Bt + (size_t)(bn + srow)*K      + k0 + scol, (char*)Bs + t*16);
    gload16(Bt + (size_t)(bn + 64 + srow)*K + k0 + scol, (char*)Bs + 4096 + t*16);
    __syncthreads();

    bf16x8 af[4], bfv[4];
#pragma unroll
    for(int m = 0; m < 4; ++m) af[m] = *(const bf16x8*)&As[aoff[m]];
#pragma unroll
    for(int n = 0; n < 4; ++n) bfv[n] = *(const bf16x8*)&Bs[boff[n]];
#pragma unroll
    for(int m = 0; m < 4; ++m)
#pragma unroll
      for(int n = 0; n < 4; ++n)
        acc[m][n] = __builtin_amdgcn_mfma_f32_16x16x32_bf16(af[m], bfv[n], acc[m][n], 0, 0, 0);
    __syncthreads();
  }

  // C write
#pragma unroll
  for(int m = 0; m < 4; ++m){
    int row0 = bm + wm*64 + m*16 + g*4;
#pragma unroll
    for(int n = 0; n < 4; ++n){
      int col = bn + wn*64 + n*16 + r;
#pragma unroll
      for(int i = 0; i < 4; ++i){
        if(row0 + i < NN){
          if(MODE == 1){
            Cb[(size_t)(row0+i)*ND + col] = bf1(acc[m][n][i]);
          } else {
            if(col < ND) Cb[(size_t)(row0+i)*ND + col] = bf1(acc[m][n][i]);
            else         Cb2[(size_t)(row0+i)*ND + (col - ND)] = bf1(acc[m][n][i]);
          }
        }
      }
    }
  }

  // fused el/er (h-columns only; block-uniform condition so the syncthreads are safe)
  if(MODE == 1 || bn < ND){
    int head = (bn >= NC) ? 1 : 0;
    float alv[4], arv[4];
#pragma unroll
    for(int n = 0; n < 4; ++n){
      int col = bn + wn*64 + n*16 + r;
      alv[n] = al[col]; arv[n] = ar[col];
    }
#pragma unroll
    for(int m = 0; m < 4; ++m){
#pragma unroll
      for(int i = 0; i < 4; ++i){
        int row = wm*64 + m*16 + g*4 + i;   // 0..127 (local)
        float pel = acc[m][0][i]*alv[0] + acc[m][1][i]*alv[1] + acc[m][2][i]*alv[2] + acc[m][3][i]*alv[3];
        float per = acc[m][0][i]*arv[0] + acc[m][1][i]*arv[1] + acc[m][2][i]*arv[2] + acc[m][3][i]*arv[3];
        red[row*32 + wn*16 + r]        = pel;
        red[4096 + row*32 + wn*16 + r] = per;
      }
    }
    __syncthreads();
    int row = t & 127;
    int base = (t < 128) ? 0 : 4096;
    float s = 0.0f;
#pragma unroll
    for(int j = 0; j < 32; ++j) s += red[base + row*32 + ((j + t) & 31)];
    int grow = bm + row;
    if(grow < NN){
      if(t < 128) el[(size_t)grow*2 + head] = s;
      else        er[(size_t)grow*2 + head] = s;
    }
  }
}

// ---------------- attention softmax + aggregate (one wave per dst node, 4-deep gather pipeline) ----------------
// bf16 residual in, bf16 out. All __shfl at FULL exec (R5/R6 lesson); select AFTER shuffles.
__global__ __launch_bounds__(256) void k_attn(const unsigned short* __restrict__ Hm, const float* __restrict__ el,
                                              const float* __restrict__ er, const int* __restrict__ rowstart,
                                              const int* __restrict__ srcS, const unsigned short* __restrict__ res,
                                              unsigned short* __restrict__ out){
  int n = blockIdx.x*4 + (threadIdx.x >> 6);
  int lane = threadIdx.x & 63;
  if(n >= NN) return;
  int rs = rowstart[n], re = rowstart[n+1];
  int deg = re - rs;
  float4 acc = cvt4(((const ushort4*)(res + (size_t)n*ND))[lane]);
  if(deg > 0){
    float er0 = er[n*2], er1 = er[n*2+1];
    if(deg <= 64){
      int s = srcS[rs + (lane < deg ? lane : 0)];
      float e0 = -1e30f, e1 = -1e30f;
      if(lane < deg){
        e0 = lrelu(el[s*2]   + er0);
        e1 = lrelu(el[s*2+1] + er1);
      }
      float m0 = e0, m1 = e1;
#pragma unroll
      for(int off = 32; off >= 1; off >>= 1){ m0 = fmaxf(m0, __shfl_xor(m0, off)); m1 = fmaxf(m1, __shfl_xor(m1, off)); }
      float x0 = (lane < deg) ? expf(e0 - m0) : 0.0f;
      float x1 = (lane < deg) ? expf(e1 - m1) : 0.0f;
      float s0 = x0, s1 = x1;
#pragma unroll
      for(int off = 32; off >= 1; off >>= 1){ s0 += __shfl_xor(s0, off); s1 += __shfl_xor(s1, off); }
      x0 *= 1.0f/(s0 + 1e-9f);
      x1 *= 1.0f/(s1 + 1e-9f);
      bool h1 = (lane >= 32);
      for(int j0 = 0; j0 < deg; j0 += 4){
        int sj0 = __shfl(s, j0+0), sj1 = __shfl(s, j0+1);
        int sj2 = __shfl(s, j0+2), sj3 = __shfl(s, j0+3);
        ushort4 g0 = ((const ushort4*)(Hm + (size_t)sj0*ND))[lane];
        ushort4 g1 = ((const ushort4*)(Hm + (size_t)sj1*ND))[lane];
        ushort4 g2 = ((const ushort4*)(Hm + (size_t)sj2*ND))[lane];
        ushort4 g3 = ((const ushort4*)(Hm + (size_t)sj3*ND))[lane];
        float a00 = __shfl(x0, j0+0), a10 = __shfl(x1, j0+0);
        float a01 = __shfl(x0, j0+1), a11 = __shfl(x1, j0+1);
        float a02 = __shfl(x0, j0+2), a12 = __shfl(x1, j0+2);
        float a03 = __shfl(x0, j0+3), a13 = __shfl(x1, j0+3);
        float w0 = h1 ? a10 : a00;
        float w1 = h1 ? a11 : a01;
        float w2 = h1 ? a12 : a02;
        float w3 = h1 ? a13 : a03;
        float4 v0 = cvt4(g0), v1 = cvt4(g1), v2 = cvt4(g2), v3 = cvt4(g3);
        acc.x += w0*v0.x + w1*v1.x + w2*v2.x + w3*v3.x;
        acc.y += w0*v0.y + w1*v1.y + w2*v2.y + w3*v3.y;
        acc.z += w0*v0.z + w1*v1.z + w2*v2.z + w3*v3.z;
        acc.w += w0*v0.w + w1*v1.w + w2*v2.w + w3*v3.w;
      }
    } else {
      float m0 = -1e30f, m1 = -1e30f;
      for(int j = lane; j < deg; j += 64){
        int s = srcS[rs + j];
        m0 = fmaxf(m0, lrelu(el[s*2]   + er0));
        m1 = fmaxf(m1, lrelu(el[s*2+1] + er1));
      }
#pragma unroll
      for(int off = 32; off >= 1; off >>= 1){ m0 = fmaxf(m0, __shfl_xor(m0, off)); m1 = fmaxf(m1, __shfl_xor(m1, off)); }
      float s0 = 0.0f, s1 = 0.0f;
      for(int j = lane; j < deg; j += 64){
        int s = srcS[rs + j];
        s0 += expf(lrelu(el[s*2]   + er0) - m0);
        s1 += expf(lrelu(el[s*2+1] + er1) - m1);
      }
#pragma unroll
      for(int off = 32; off >= 1; off >>= 1){ s0 += __shfl_xor(s0, off); s1 += __shfl_xor(s1, off); }
      float inv = (lane < 32) ? 1.0f/(s0 + 1e-9f) : 1.0f/(s1 + 1e-9f);
      float mh  = (lane < 32) ? m0 : m1;
      for(int j = 0; j < deg; ++j){
        int s = srcS[rs + j];
        float e = (lane < 32) ? lrelu(el[s*2] + er0) : lrelu(el[s*2+1] + er1);
        float a = expf(e - mh) * inv;
        float4 hv = cvt4(((const ushort4*)(Hm + (size_t)s*ND))[lane]);
        acc.x += a*hv.x; acc.y += a*hv.y; acc.z += a*hv.z; acc.w += a*hv.w;
      }
    }
  }
  uint2 pk; pk.x = bfpair(acc.x, acc.y); pk.y = bfpair(acc.z, acc.w);
  ((uint2*)(out + (size_t)n*ND))[lane] = pk;
}

// ---------------- per-graph column stats (bf16 input): coalesced rows + LDS reduce + few atomics ----------------
__global__ __launch_bounds__(256) void k_gstats(const unsigned short* __restrict__ X, const int* __restrict__ gid,
                                                float* __restrict__ gsum, float* __restrict__ gsq){
  __shared__ f32x4 reds[256];
  __shared__ f32x4 redq[256];
  int tid = threadIdx.x;
  int f4 = tid & 63;
  int r  = tid >> 6;
  int n0 = blockIdx.x * 125;
  int g0 = gid[n0];
  f32x4 s0 = {0,0,0,0}, q0 = {0,0,0,0};
  f32x4 s1 = {0,0,0,0}, q1 = {0,0,0,0};
  int cg1 = -1;
  for(int n = n0 + r; n < n0 + 125; n += 4){
    int g = gid[n];
    float4 vv = cvt4(*(const ushort4*)(X + (size_t)n*ND + f4*4));
    f32x4 v = {vv.x, vv.y, vv.z, vv.w};
    if(g == g0){ s0 += v; q0 += v*v; }
    else {
      if(g != cg1){
        if(cg1 >= 0){
#pragma unroll
          for(int j = 0; j < 4; ++j){
            atomicAdd(&gsum[cg1*ND + f4*4 + j], s1[j]);
            atomicAdd(&gsq [cg1*ND + f4*4 + j], q1[j]);
          }
        }
        cg1 = g; s1 = (f32x4){0,0,0,0}; q1 = (f32x4){0,0,0,0};
      }
      s1 += v; q1 += v*v;
    }
  }
  if(cg1 >= 0){
#pragma unroll
    for(int j = 0; j < 4; ++j){
      atomicAdd(&gsum[cg1*ND + f4*4 + j], s1[j]);
      atomicAdd(&gsq [cg1*ND + f4*4 + j], q1[j]);
    }
  }
  reds[tid] = s0; redq[tid] = q0;
  __syncthreads();
  if(r == 0){
    f32x4 ts = reds[f4] + reds[f4+64] + reds[f4+128] + reds[f4+192];
    f32x4 tq = redq[f4] + redq[f4+64] + redq[f4+128] + redq[f4+192];
#pragma unroll
    for(int j = 0; j < 4; ++j){
      atomicAdd(&gsum[g0*ND + f4*4 + j], ts[j]);
      atomicAdd(&gsq [g0*ND + f4*4 + j], tq[j]);
    }
  }
}

// ---------------- finstats: 41 blocks (40 per-graph + 1 batch), pure-read, no reset ----------------
__global__ __launch_bounds__(256) void k_finstats(const float* __restrict__ gsum, const float* __restrict__ gsq,
                                                  const int* __restrict__ cnt, float* __restrict__ gmean,
                                                  float* __restrict__ grs, float* __restrict__ bnm,
                                                  float* __restrict__ bnrs){
  int d = threadIdx.x; // 256
  int b = blockIdx.x;
  if(b < NG){
    float c = (float)cnt[b];
    float s = gsum[b*ND + d], q = gsq[b*ND + d];
    float m = s / c;
    float v = q / c - m*m;
    gmean[b*ND + d] = m;
    grs[b*ND + d] = rsqrtf(fmaxf(v, 0.0f) + EPSF);
  } else {
    float ts = 0.0f, tq = 0.0f;
    for(int g = 0; g < NG; ++g){ ts += gsum[g*ND + d]; tq += gsq[g*ND + d]; }
    float bm = ts / (float)NN;
    float bv = tq / (float)NN - bm*bm;
    bnm[d] = bm;
    bnrs[d] = rsqrtf(fmaxf(bv, 0.0f) + EPSF);
  }
}

// ---------------- united norm apply (+ leaky) ----------------
// bf16 X in. LAYER<2: single bf16 out (residual AND next GEMM A, pad rows zeroed).
// LAYER==2: fp32 head_mean out.
template<int LAYER>
__global__ __launch_bounds__(256) void k_norm(const unsigned short* __restrict__ X, const int* __restrict__ gid,
    const float* __restrict__ gmean, const float* __restrict__ grs, const float* __restrict__ bnm,
    const float* __restrict__ bnrs, const float* __restrict__ gamma, const float* __restrict__ beta,
    const float* __restrict__ lbn, const float* __restrict__ lgn, const float* __restrict__ lnn,
    unsigned short* __restrict__ outb, float* __restrict__ outf){
  int n = blockIdx.x*4 + (threadIdx.x >> 6);
  int lane = threadIdx.x & 63;
  if(n >= NPAD) return;
  if(n >= NN){
    if(LAYER < 2){ uint2 z = {0,0}; ((uint2*)(outb + (size_t)n*ND))[lane] = z; }
    return;
  }
  float4 v = cvt4(((const ushort4*)(X + (size_t)n*ND))[lane]);
  float s = v.x + v.y + v.z + v.w;
  float q = v.x*v.x + v.y*v.y + v.z*v.z + v.w*v.w;
#pragma unroll
  for(int off = 32; off >= 1; off >>= 1){ s += __shfl_xor(s, off); q += __shfl_xor(q, off); }
  float nm = s * (1.0f/ND);
  float nv = q * (1.0f/ND) - nm*nm;
  float nrs = rsqrtf(fmaxf(nv, 0.0f) + EPSF);
  int g = gid[n];
  float4 gm = ((const float4*)(gmean + g*ND))[lane];
  float4 gr = ((const float4*)(grs   + g*ND))[lane];
  float4 bm = ((const float4*)bnm)[lane];
  float4 br = ((const float4*)bnrs)[lane];
  float4 ga = ((const float4*)gamma)[lane];
  float4 be = ((const float4*)beta)[lane];
  float4 lb = ((const float4*)lbn)[lane];
  float4 lg = ((const float4*)lgn)[lane];
  float4 ln = ((const float4*)lnn)[lane];
  float4 o;
  o.x = lrelu(ga.x*(lb.x*((v.x-bm.x)*br.x) + lg.x*((v.x-gm.x)*gr.x) + ln.x*((v.x-nm)*nrs)) + be.x);
  o.y = lrelu(ga.y*(lb.y*((v.y-bm.y)*br.y) + lg.y*((v.y-gm.y)*gr.y) + ln.y*((v.y-nm)*nrs)) + be.y);
  o.z = lrelu(ga.z*(lb.z*((v.z-bm.z)*br.z) + lg.z*((v.z-gm.z)*gr.z) + ln.z*((v.z-nm)*nrs)) + be.z);
  o.w = lrelu(ga.w*(lb.w*((v.w-bm.w)*br.w) + lg.w*((v.w-gm.w)*gr.w) + ln.w*((v.w-nm)*nrs)) + be.w);
  if(LAYER < 2){
    uint2 pk; pk.x = bfpair(o.x, o.y); pk.y = bfpair(o.z, o.w);
    ((uint2*)(outb + (size_t)n*ND))[lane] = pk;
  } else {
    float4 p;
    p.x = __shfl_xor(o.x, 32); p.y = __shfl_xor(o.y, 32);
    p.z = __shfl_xor(o.z, 32); p.w = __shfl_xor(o.w, 32);
    if(lane < 32){
      float4 hm;
      hm.x = 0.5f*(o.x + p.x); hm.y = 0.5f*(o.y + p.y);
      hm.z = 0.5f*(o.z + p.z); hm.w = 0.5f*(o.w + p.w);
      ((float4*)(outf + (size_t)n*NC))[lane] = hm;
    }
  }
}

// ---------------- graph readout ----------------
__global__ void k_readout_part(const float* __restrict__ HM, const int* __restrict__ gid,
                               const int* __restrict__ gmn, const int* __restrict__ gmx,
                               float* __restrict__ obuf){
  int g = blockIdx.x >> 3, part = blockIdx.x & 7;
  int c = threadIdx.x; // 128
  int n0 = gmn[g], n1 = gmx[g] + 1;
  int len = n1 - n0;
  int beg = n0 + (int)(((long)len * part) >> 3);
  int end = n0 + (int)(((long)len * (part+1)) >> 3);
  float acc = 0.0f;
  for(int n = beg; n < end; ++n){
    if(gid[n] == g) acc += HM[(size_t)n*NC + c];
  }
  atomicAdd(&obuf[g*NC + c], acc);
}

__global__ void k_readout_fin(const float* __restrict__ obuf, const int* __restrict__ cnt,
                              float* __restrict__ outp){
  int i = blockIdx.x*128 + threadIdx.x; // NG*NC
  int g = i / NC;
  outp[i] = lrelu(obuf[i] / (float)cnt[g]);
}

// ---------------- launch ----------------
extern "C" void kernel_launch(void* const* d_in, const int* in_sizes, int n_in,
                              void* d_out, int out_size, void* d_ws, size_t ws_size,
                              hipStream_t stream){
  const float* X0  = (const float*)d_in[0];
  const int* src   = (const int*)d_in[1];
  const int* dst   = (const int*)d_in[2];
  const int* gid   = (const int*)d_in[3];
  const float* Wm[3] = { (const float*)d_in[4], (const float*)d_in[5], (const float*)d_in[6] };
  const float* resW  = (const float*)d_in[7];
  const float *AL[3], *AR[3], *GA[3], *BE[3], *LB[3], *LG[3], *LN[3];
  for(int i = 0; i < 3; ++i){
    int b = 8 + i*7;
    AL[i] = (const float*)d_in[b];   AR[i] = (const float*)d_in[b+1];
    GA[i] = (const float*)d_in[b+2]; BE[i] = (const float*)d_in[b+3];
    LB[i] = (const float*)d_in[b+4]; LG[i] = (const float*)d_in[b+5]; LN[i] = (const float*)d_in[b+6];
  }
  float* out = (float*)d_out;

  // workspace layout (all node-feature intermediates bf16)
  float* wf = (float*)d_ws;
  unsigned short* Hbf  = (unsigned short*)wf;  wf += (size_t)NN*ND/2;    // h bf16
  unsigned short* XAb  = (unsigned short*)wf;  wf += (size_t)NN*ND/2;    // attn out bf16; L0 A-staging
  unsigned short* XBb  = (unsigned short*)wf;  wf += (size_t)NPAD*ND/2;  // norm out bf16 (residual + GEMM A)
  unsigned short* RESb = (unsigned short*)wf;  wf += (size_t)NN*ND/2;    // L0 residual bf16; later head_mean fp32
  float* el   = wf;                 wf += (size_t)NN*2;
  float* er   = wf;                 wf += (size_t)NN*2;
  float* gsum = wf;                 wf += 3*NG*ND;   // per-layer (no reset needed)
  float* gsq  = wf;                 wf += 3*NG*ND;
  float* gmean= wf;                 wf += NG*ND;
  float* grs  = wf;                 wf += NG*ND;
  float* bnm  = wf;                 wf += ND;
  float* bnrs = wf;                 wf += ND;
  float* obuf = wf;                 wf += NG*NC;
  unsigned short* Bt0 = (unsigned short*)wf; wf += (2*ND*NC)/2;   // 512x128 bf16
  unsigned short* Bt1 = (unsigned short*)wf; wf += (ND*ND)/2;     // 256x256 bf16
  unsigned short* Bt2 = (unsigned short*)wf; wf += (ND*ND)/2;     // 256x256 bf16
  int* ip = (int*)wf;
  int* deg      = ip;               ip += NN;
  int* rowstart = ip;               ip += NN + 1;
  int* cur      = ip;               ip += NN;
  int* srcS     = ip;               ip += NE;
  int* cnt      = ip;               ip += NG;
  int* gmn      = ip;               ip += NG;
  int* gmx      = ip;               ip += NG;
  int* bsum     = ip;               ip += SCAN_NB;
  int* boff     = ip;               ip += SCAN_NB;

  unsigned short* A0bf = XAb;            // L0 bf16 A staging (GEMM consumes before attn overwrites)
  float* HMf = (float*)RESb;             // L2 head_mean fp32 (NN*NC floats fit in NN*ND/2 ushort slots)

  // ---- prep (incl. zero-init) + CSR + graph meta ----
  k_prep<<<2600, 256, 0, stream>>>(X0, Wm[0], resW, Wm[1], Wm[2], (unsigned int*)A0bf, Bt0, Bt1, Bt2,
                                   deg, cur, cnt, gmn, gmx, gsum, gsq, obuf);
  k_hist<<<2500, 256, 0, stream>>>(dst, gid, deg, cnt, gmn, gmx);
  k_scan_a<<<SCAN_NB, 256, 0, stream>>>(deg, bsum);
  k_scan_b<<<1, 256, 0, stream>>>(bsum, boff, rowstart);
  k_scan_c<<<SCAN_NB, 256, 0, stream>>>(deg, boff, rowstart);
  k_fill<<<(NE+255)/256, 256, 0, stream>>>(src, dst, rowstart, cur, srcS);

  for(int L = 0; L < 3; ++L){
    float* gsumL = gsum + (size_t)L*NG*ND;
    float* gsqL  = gsq  + (size_t)L*NG*ND;
    if(L == 0){
      dim3 g0(NPAD/128, 4);  // cols 0..255 -> Hbf, 256..511 -> RESb (bf16 residual)
      k_gemm_bf16<NC,2><<<g0, 256, 0, stream>>>(A0bf, Bt0, RESb, Hbf, AL[0], AR[0], el, er);
    } else {
      dim3 g1(NPAD/128, 2);
      k_gemm_bf16<ND,1><<<g1, 256, 0, stream>>>(XBb, (L == 1) ? Bt1 : Bt2, nullptr, Hbf, AL[L], AR[L], el, er);
    }
    const unsigned short* resp = (L == 0) ? RESb : XBb;
    k_attn<<<NN/4, 256, 0, stream>>>(Hbf, el, er, rowstart, srcS, resp, XAb);
    k_gstats<<<NN/125, 256, 0, stream>>>(XAb, gid, gsumL, gsqL);
    k_finstats<<<NG+1, 256, 0, stream>>>(gsumL, gsqL, cnt, gmean, grs, bnm, bnrs);
    if(L == 0)      k_norm<0><<<NPAD/4, 256, 0, stream>>>(XAb, gid, gmean, grs, bnm, bnrs, GA[0], BE[0], LB[0], LG[0], LN[0], XBb, nullptr);
    else if(L == 1) k_norm<1><<<NPAD/4, 256, 0, stream>>>(XAb, gid, gmean, grs, bnm, bnrs, GA[1], BE[1], LB[1], LG[1], LN[1], XBb, nullptr);
    else            k_norm<2><<<NN/4, 256, 0, stream>>>(XAb, gid, gmean, grs, bnm, bnrs, GA[2], BE[2], LB[2], LG[2], LN[2], nullptr, HMf);
  }
  k_readout_part<<<NG*8, NC, 0, stream>>>(HMf, gid, gmn, gmx, obuf);
  k_readout_fin<<<NG, NC, 0, stream>>>(obuf, cnt, out);
}

// Round 14
// 422.857 us; speedup vs baseline: 1.4871x; 1.0284x over previous
//
#include <hip/hip_runtime.h>
#include <math.h>

#define NN 40000
#define NPAD 40064   // 313 * 128
#define NE 640000
#define NG 40
#define NC 128
#define ND 256
#define SLOPEF 0.2f
#define EPSF 1e-5f
#define SCAN_NB 157  // ceil(40000/256)

typedef short bf16x8 __attribute__((ext_vector_type(8)));
typedef float f32x4 __attribute__((ext_vector_type(4)));

static __device__ __forceinline__ float lrelu(float x){ return x >= 0.0f ? x : SLOPEF * x; }

static __device__ __forceinline__ unsigned int bfpair(float a, float b){
  unsigned int ua = __float_as_uint(a);
  ua = (ua + 0x7fffu + ((ua >> 16) & 1u)) >> 16;
  unsigned int ub = __float_as_uint(b);
  ub = (ub + 0x7fffu + ((ub >> 16) & 1u)) >> 16;
  return ua | (ub << 16);
}
static __device__ __forceinline__ unsigned short bf1(float x){
  unsigned int u = __float_as_uint(x);
  return (unsigned short)((u + 0x7fffu + ((u >> 16) & 1u)) >> 16);
}
static __device__ __forceinline__ float4 cvt4(ushort4 v){
  float4 o;
  o.x = __uint_as_float(((unsigned)v.x) << 16);
  o.y = __uint_as_float(((unsigned)v.y) << 16);
  o.z = __uint_as_float(((unsigned)v.z) << 16);
  o.w = __uint_as_float(((unsigned)v.w) << 16);
  return o;
}

static __device__ __forceinline__ void gload16(const void* gsrc, void* lds){
  __builtin_amdgcn_global_load_lds(
      (const __attribute__((address_space(1))) void*)gsrc,
      (__attribute__((address_space(3))) void*)lds, 16, 0, 0);
}

// ---------------- merged histogram: edge degree + graph count/min/max ----------------
__global__ __launch_bounds__(256) void k_hist(const int* __restrict__ dst, const int* __restrict__ gid,
                                              int* __restrict__ deg, int* __restrict__ cnt,
                                              int* __restrict__ gmn, int* __restrict__ gmx){
  __shared__ int lc[NG], lmn[NG], lmx[NG];
  int tid = threadIdx.x;
  for(int i = tid; i < NG; i += 256){ lc[i] = 0; lmn[i] = 0x7f7f7f7f; lmx[i] = -1; }
  __syncthreads();
  int stride = gridDim.x*256;
  int base = blockIdx.x*256 + tid;
  for(int n = base; n < NN; n += stride){
    int g = gid[n];
    atomicAdd(&lc[g], 1);
    atomicMin(&lmn[g], n);
    atomicMax(&lmx[g], n);
  }
  for(int e = base; e < NE; e += stride) atomicAdd(&deg[dst[e]], 1);
  __syncthreads();
  for(int i = tid; i < NG; i += 256){
    if(lc[i] > 0){
      atomicAdd(&cnt[i], lc[i]);
      atomicMin(&gmn[i], lmn[i]);
      atomicMax(&gmx[i], lmx[i]);
    }
  }
}

// -------- multi-block exclusive scan of deg[NN] -> rowstart[NN+1] --------
__global__ __launch_bounds__(256) void k_scan_a(const int* __restrict__ deg, int* __restrict__ bsum){
  int tid = threadIdx.x;
  int i = blockIdx.x*256 + tid;
  int v = (i < NN) ? deg[i] : 0;
#pragma unroll
  for(int off = 32; off >= 1; off >>= 1) v += __shfl_xor(v, off);
  __shared__ int ws[4];
  if((tid & 63) == 0) ws[tid >> 6] = v;
  __syncthreads();
  if(tid == 0) bsum[blockIdx.x] = ws[0] + ws[1] + ws[2] + ws[3];
}

__global__ __launch_bounds__(256) void k_scan_b(int* __restrict__ bsum, int* __restrict__ boff,
                                                int* __restrict__ rowstart){
  __shared__ int lds[256];
  int tid = threadIdx.x;
  int v = (tid < SCAN_NB) ? bsum[tid] : 0;
  lds[tid] = v;
  __syncthreads();
  for(int off = 1; off < 256; off <<= 1){
    int t = (tid >= off) ? lds[tid - off] : 0;
    __syncthreads();
    lds[tid] += t;
    __syncthreads();
  }
  if(tid < SCAN_NB) boff[tid] = lds[tid] - v;  // exclusive
  if(tid == SCAN_NB - 1) rowstart[NN] = lds[tid];
}

__global__ __launch_bounds__(256) void k_scan_c(const int* __restrict__ deg, const int* __restrict__ boff,
                                                int* __restrict__ rowstart){
  __shared__ int lds[256];
  int tid = threadIdx.x;
  int i = blockIdx.x*256 + tid;
  int v = (i < NN) ? deg[i] : 0;
  lds[tid] = v;
  __syncthreads();
  for(int off = 1; off < 256; off <<= 1){
    int t = (tid >= off) ? lds[tid - off] : 0;
    __syncthreads();
    lds[tid] += t;
    __syncthreads();
  }
  if(i < NN) rowstart[i] = boff[blockIdx.x] + lds[tid] - v;
}

__global__ void k_fill(const int* __restrict__ src, const int* __restrict__ dst,
                       const int* __restrict__ rowstart, int* __restrict__ cur, int* __restrict__ srcS){
  int e = blockIdx.x*256 + threadIdx.x;
  if(e < NE){
    int d = dst[e];
    int slot = rowstart[d] + atomicAdd(&cur[d], 1);
    srcS[slot] = src[e];
  }
}

// ---------------- upfront prep: zero-init + X0->bf16 A + all weight transposes ----------------
#define PREP_A  (NPAD*NC/8)          // 641024
#define PREP_W0 (2*ND*NC/8)          // 8192
#define PREP_W  (ND*ND/8)            // 8192
__global__ __launch_bounds__(256) void k_prep(const float* __restrict__ X0,
                                              const float* __restrict__ W0, const float* __restrict__ Wr,
                                              const float* __restrict__ W1, const float* __restrict__ W2,
                                              unsigned int* __restrict__ A0,
                                              unsigned short* __restrict__ Bt0,
                                              unsigned short* __restrict__ Bt1,
                                              unsigned short* __restrict__ Bt2,
                                              int* __restrict__ deg, int* __restrict__ cur,
                                              int* __restrict__ cnt, int* __restrict__ gmn,
                                              int* __restrict__ gmx, float* __restrict__ gsum,
                                              float* __restrict__ gsq, float* __restrict__ obuf){
  int i0 = blockIdx.x*256 + threadIdx.x;
  int stride = gridDim.x*256;
  for(int j = i0; j < NN; j += stride){ deg[j] = 0; cur[j] = 0; }
  for(int j = i0; j < NG; j += stride){ cnt[j] = 0; gmn[j] = 0x7f7f7f7f; gmx[j] = -1; }
  for(int j = i0; j < 3*NG*ND; j += stride){ gsum[j] = 0.0f; gsq[j] = 0.0f; }
  for(int j = i0; j < NG*NC; j += stride){ obuf[j] = 0.0f; }
  int total = PREP_A + PREP_W0 + 2*PREP_W;
  for(int i = i0; i < total; i += stride){
    if(i < PREP_A){
      long e8 = (long)i * 8;
      int row = (int)(e8 / NC);
      int col = (int)(e8 - (long)row * NC);
      uint4 o;
      if(row < NN){
        const float4* p = (const float4*)(X0 + (size_t)row*NC + col);
        float4 v0 = p[0], v1 = p[1];
        o.x = bfpair(v0.x, v0.y); o.y = bfpair(v0.z, v0.w);
        o.z = bfpair(v1.x, v1.y); o.w = bfpair(v1.z, v1.w);
      } else o = make_uint4(0,0,0,0);
      ((uint4*)A0)[i] = o;
    } else if(i < PREP_A + PREP_W0){
      int j = i - PREP_A;
      int c = j >> 4;                 // NC/8 = 16
      int k0 = (j & 15) * 8;
      const float* W = (c < ND) ? W0 : Wr;
      int cc = c & (ND-1);
      float v[8];
#pragma unroll
      for(int u = 0; u < 8; ++u) v[u] = W[(size_t)(k0+u)*ND + cc];
      uint4 o;
      o.x = bfpair(v[0], v[1]); o.y = bfpair(v[2], v[3]);
      o.z = bfpair(v[4], v[5]); o.w = bfpair(v[6], v[7]);
      *((uint4*)(Bt0 + (size_t)c*NC + k0)) = o;
    } else {
      int j = i - PREP_A - PREP_W0;
      const float* W = (j < PREP_W) ? W1 : W2;
      unsigned short* Bt = (j < PREP_W) ? Bt1 : Bt2;
      j &= (PREP_W - 1);
      int c = j >> 5;                 // ND/8 = 32
      int k0 = (j & 31) * 8;
      float v[8];
#pragma unroll
      for(int u = 0; u < 8; ++u) v[u] = W[(size_t)(k0+u)*ND + c];
      uint4 o;
      o.x = bfpair(v[0], v[1]); o.y = bfpair(v[2], v[3]);
      o.z = bfpair(v[4], v[5]); o.w = bfpair(v[6], v[7]);
      *((uint4*)(Bt + (size_t)c*ND + k0)) = o;
    }
  }
}

// ---------------- bf16 MFMA GEMM: 128x256 tile, 512 threads (8 waves 2x4), A read once ----------------
// MODE 1 (L1/L2, grid (313,1)): all 256 cols -> Cb (h), el/er fused.
// MODE 2 (L0, grid (313,2)): by=0 -> h cols + el/er; by=1 -> residual cols -> Cb2.
template<int K, int MODE>
__global__ __launch_bounds__(512) void k_gemm_bf16(const unsigned short* __restrict__ A,
                                                   const unsigned short* __restrict__ Bt,
                                                   unsigned short* __restrict__ Cb2,
                                                   unsigned short* __restrict__ Cb,
                                                   const float* __restrict__ al,
                                                   const float* __restrict__ ar,
                                                   float* __restrict__ el,
                                                   float* __restrict__ er){
  __shared__ float red[8192];                       // 32 KB; first 24 KB doubles as staging
  unsigned short* As = (unsigned short*)red;        // 128x32 ushort = 8 KB
  unsigned short* Bs = As + 4096;                   // 256x32 ushort = 16 KB
  int t = threadIdx.x;                              // 0..511
  int lane = t & 63, wid = t >> 6;                  // 8 waves
  int wm = wid & 1, wn = wid >> 1;                  // 2 x 4
  int r = lane & 15, g = lane >> 4;
  int bm = blockIdx.x * 128;
  int bn = blockIdx.y * 256;                        // 0 (h) or 256 (L0 residual)

  int aoff[4], boff[4];
#pragma unroll
  for(int m = 0; m < 4; ++m) aoff[m] = ((wm*64 + m*16 + r) << 5) + (g << 3);
#pragma unroll
  for(int n = 0; n < 4; ++n) boff[n] = ((wn*64 + n*16 + r) << 5) + (g << 3);

  f32x4 acc[4][4] = {};

  for(int k0 = 0; k0 < K; k0 += 32){
    // A tile 128x32: 512 chunks of 16B, one per thread
    gload16(A + (size_t)(bm + (t >> 2))*K + k0 + (t & 3)*8, (char*)As + t*16);
    // B tile 256x32: 1024 chunks, two per thread
    {
      int i1 = t, i2 = t + 512;
      gload16(Bt + (size_t)(bn + (i1 >> 2))*K + k0 + (i1 & 3)*8, (char*)Bs + i1*16);
      gload16(Bt + (size_t)(bn + (i2 >> 2))*K + k0 + (i2 & 3)*8, (char*)Bs + i2*16);
    }
    __syncthreads();

    bf16x8 af[4], bfv[4];
#pragma unroll
    for(int m = 0; m < 4; ++m) af[m] = *(const bf16x8*)&As[aoff[m]];
#pragma unroll
    for(int n = 0; n < 4; ++n) bfv[n] = *(const bf16x8*)&Bs[boff[n]];
#pragma unroll
    for(int m = 0; m < 4; ++m)
#pragma unroll
      for(int n = 0; n < 4; ++n)
        acc[m][n] = __builtin_amdgcn_mfma_f32_16x16x32_bf16(af[m], bfv[n], acc[m][n], 0, 0, 0);
    __syncthreads();
  }

  // C write (per-block uniform destination)
#pragma unroll
  for(int m = 0; m < 4; ++m){
    int row0 = bm + wm*64 + m*16 + g*4;
#pragma unroll
    for(int n = 0; n < 4; ++n){
      int lcol = wn*64 + n*16 + r;   // 0..255 local
#pragma unroll
      for(int i = 0; i < 4; ++i){
        if(row0 + i < NN){
          if(MODE == 1 || bn < ND) Cb[(size_t)(row0+i)*ND + lcol] = bf1(acc[m][n][i]);
          else                     Cb2[(size_t)(row0+i)*ND + lcol] = bf1(acc[m][n][i]);
        }
      }
    }
  }

  // fused el/er (only h blocks; block-uniform). wave head: wn<2 -> head0, wn>=2 -> head1.
  if(MODE == 1 || bn < ND){
    int head = (wn >= 2) ? 1 : 0;
    float alv[4], arv[4];
#pragma unroll
    for(int n = 0; n < 4; ++n){
      int col = wn*64 + n*16 + r;    // global col (bn==0 here)
      alv[n] = al[col]; arv[n] = ar[col];
    }
    // ---- pass 1: el ----
    __syncthreads();   // ensure all waves done with As/Bs (post K-loop reads finished)
#pragma unroll
    for(int m = 0; m < 4; ++m){
#pragma unroll
      for(int i = 0; i < 4; ++i){
        int row = wm*64 + m*16 + g*4 + i;   // 0..127 local
        float pel = acc[m][0][i]*alv[0] + acc[m][1][i]*alv[1] + acc[m][2][i]*alv[2] + acc[m][3][i]*alv[3];
        red[row*64 + wn*16 + r] = pel;      // slots: head0 -> 0..31, head1 -> 32..63
      }
    }
    __syncthreads();
    if(t < 256){
      int row = t & 127, hd = t >> 7;
      float s = 0.0f;
#pragma unroll
      for(int j = 0; j < 32; ++j) s += red[row*64 + hd*32 + ((j + t) & 31)];
      int grow = bm + row;
      if(grow < NN) el[(size_t)grow*2 + hd] = s;
    }
    __syncthreads();
    // ---- pass 2: er ----
#pragma unroll
    for(int m = 0; m < 4; ++m){
#pragma unroll
      for(int i = 0; i < 4; ++i){
        int row = wm*64 + m*16 + g*4 + i;
        float per = acc[m][0][i]*arv[0] + acc[m][1][i]*arv[1] + acc[m][2][i]*arv[2] + acc[m][3][i]*arv[3];
        red[row*64 + wn*16 + r] = per;
      }
    }
    __syncthreads();
    if(t < 256){
      int row = t & 127, hd = t >> 7;
      float s = 0.0f;
#pragma unroll
      for(int j = 0; j < 32; ++j) s += red[row*64 + hd*32 + ((j + t) & 31)];
      int grow = bm + row;
      if(grow < NN) er[(size_t)grow*2 + hd] = s;
    }
  }
}

// ---------------- attention softmax + aggregate (one wave per dst node, 4-deep gather pipeline) ----------------
// bf16 residual in, bf16 out. All __shfl at FULL exec (R5/R6 lesson); select AFTER shuffles.
__global__ __launch_bounds__(256) void k_attn(const unsigned short* __restrict__ Hm, const float* __restrict__ el,
                                              const float* __restrict__ er, const int* __restrict__ rowstart,
                                              const int* __restrict__ srcS, const unsigned short* __restrict__ res,
                                              unsigned short* __restrict__ out){
  int n = blockIdx.x*4 + (threadIdx.x >> 6);
  int lane = threadIdx.x & 63;
  if(n >= NN) return;
  int rs = rowstart[n], re = rowstart[n+1];
  int deg = re - rs;
  float4 acc = cvt4(((const ushort4*)(res + (size_t)n*ND))[lane]);
  if(deg > 0){
    float er0 = er[n*2], er1 = er[n*2+1];
    if(deg <= 64){
      int s = srcS[rs + (lane < deg ? lane : 0)];
      float e0 = -1e30f, e1 = -1e30f;
      if(lane < deg){
        e0 = lrelu(el[s*2]   + er0);
        e1 = lrelu(el[s*2+1] + er1);
      }
      float m0 = e0, m1 = e1;
#pragma unroll
      for(int off = 32; off >= 1; off >>= 1){ m0 = fmaxf(m0, __shfl_xor(m0, off)); m1 = fmaxf(m1, __shfl_xor(m1, off)); }
      float x0 = (lane < deg) ? expf(e0 - m0) : 0.0f;
      float x1 = (lane < deg) ? expf(e1 - m1) : 0.0f;
      float s0 = x0, s1 = x1;
#pragma unroll
      for(int off = 32; off >= 1; off >>= 1){ s0 += __shfl_xor(s0, off); s1 += __shfl_xor(s1, off); }
      x0 *= 1.0f/(s0 + 1e-9f);
      x1 *= 1.0f/(s1 + 1e-9f);
      bool h1 = (lane >= 32);
      for(int j0 = 0; j0 < deg; j0 += 4){
        int sj0 = __shfl(s, j0+0), sj1 = __shfl(s, j0+1);
        int sj2 = __shfl(s, j0+2), sj3 = __shfl(s, j0+3);
        ushort4 g0 = ((const ushort4*)(Hm + (size_t)sj0*ND))[lane];
        ushort4 g1 = ((const ushort4*)(Hm + (size_t)sj1*ND))[lane];
        ushort4 g2 = ((const ushort4*)(Hm + (size_t)sj2*ND))[lane];
        ushort4 g3 = ((const ushort4*)(Hm + (size_t)sj3*ND))[lane];
        float a00 = __shfl(x0, j0+0), a10 = __shfl(x1, j0+0);
        float a01 = __shfl(x0, j0+1), a11 = __shfl(x1, j0+1);
        float a02 = __shfl(x0, j0+2), a12 = __shfl(x1, j0+2);
        float a03 = __shfl(x0, j0+3), a13 = __shfl(x1, j0+3);
        float w0 = h1 ? a10 : a00;
        float w1 = h1 ? a11 : a01;
        float w2 = h1 ? a12 : a02;
        float w3 = h1 ? a13 : a03;
        float4 v0 = cvt4(g0), v1 = cvt4(g1), v2 = cvt4(g2), v3 = cvt4(g3);
        acc.x += w0*v0.x + w1*v1.x + w2*v2.x + w3*v3.x;
        acc.y += w0*v0.y + w1*v1.y + w2*v2.y + w3*v3.y;
        acc.z += w0*v0.z + w1*v1.z + w2*v2.z + w3*v3.z;
        acc.w += w0*v0.w + w1*v1.w + w2*v2.w + w3*v3.w;
      }
    } else {
      float m0 = -1e30f, m1 = -1e30f;
      for(int j = lane; j < deg; j += 64){
        int s = srcS[rs + j];
        m0 = fmaxf(m0, lrelu(el[s*2]   + er0));
        m1 = fmaxf(m1, lrelu(el[s*2+1] + er1));
      }
#pragma unroll
      for(int off = 32; off >= 1; off >>= 1){ m0 = fmaxf(m0, __shfl_xor(m0, off)); m1 = fmaxf(m1, __shfl_xor(m1, off)); }
      float s0 = 0.0f, s1 = 0.0f;
      for(int j = lane; j < deg; j += 64){
        int s = srcS[rs + j];
        s0 += expf(lrelu(el[s*2]   + er0) - m0);
        s1 += expf(lrelu(el[s*2+1] + er1) - m1);
      }
#pragma unroll
      for(int off = 32; off >= 1; off >>= 1){ s0 += __shfl_xor(s0, off); s1 += __shfl_xor(s1, off); }
      float inv = (lane < 32) ? 1.0f/(s0 + 1e-9f) : 1.0f/(s1 + 1e-9f);
      float mh  = (lane < 32) ? m0 : m1;
      for(int j = 0; j < deg; ++j){
        int s = srcS[rs + j];
        float e = (lane < 32) ? lrelu(el[s*2] + er0) : lrelu(el[s*2+1] + er1);
        float a = expf(e - mh) * inv;
        float4 hv = cvt4(((const ushort4*)(Hm + (size_t)s*ND))[lane]);
        acc.x += a*hv.x; acc.y += a*hv.y; acc.z += a*hv.z; acc.w += a*hv.w;
      }
    }
  }
  uint2 pk; pk.x = bfpair(acc.x, acc.y); pk.y = bfpair(acc.z, acc.w);
  ((uint2*)(out + (size_t)n*ND))[lane] = pk;
}

// ---------------- per-graph column stats (bf16 input): coalesced rows + LDS reduce + few atomics ----------------
__global__ __launch_bounds__(256) void k_gstats(const unsigned short* __restrict__ X, const int* __restrict__ gid,
                                                float* __restrict__ gsum, float* __restrict__ gsq){
  __shared__ f32x4 reds[256];
  __shared__ f32x4 redq[256];
  int tid = threadIdx.x;
  int f4 = tid & 63;
  int r  = tid >> 6;
  int n0 = blockIdx.x * 125;
  int g0 = gid[n0];
  f32x4 s0 = {0,0,0,0}, q0 = {0,0,0,0};
  f32x4 s1 = {0,0,0,0}, q1 = {0,0,0,0};
  int cg1 = -1;
  for(int n = n0 + r; n < n0 + 125; n += 4){
    int g = gid[n];
    float4 vv = cvt4(*(const ushort4*)(X + (size_t)n*ND + f4*4));
    f32x4 v = {vv.x, vv.y, vv.z, vv.w};
    if(g == g0){ s0 += v; q0 += v*v; }
    else {
      if(g != cg1){
        if(cg1 >= 0){
#pragma unroll
          for(int j = 0; j < 4; ++j){
            atomicAdd(&gsum[cg1*ND + f4*4 + j], s1[j]);
            atomicAdd(&gsq [cg1*ND + f4*4 + j], q1[j]);
          }
        }
        cg1 = g; s1 = (f32x4){0,0,0,0}; q1 = (f32x4){0,0,0,0};
      }
      s1 += v; q1 += v*v;
    }
  }
  if(cg1 >= 0){
#pragma unroll
    for(int j = 0; j < 4; ++j){
      atomicAdd(&gsum[cg1*ND + f4*4 + j], s1[j]);
      atomicAdd(&gsq [cg1*ND + f4*4 + j], q1[j]);
    }
  }
  reds[tid] = s0; redq[tid] = q0;
  __syncthreads();
  if(r == 0){
    f32x4 ts = reds[f4] + reds[f4+64] + reds[f4+128] + reds[f4+192];
    f32x4 tq = redq[f4] + redq[f4+64] + redq[f4+128] + redq[f4+192];
#pragma unroll
    for(int j = 0; j < 4; ++j){
      atomicAdd(&gsum[g0*ND + f4*4 + j], ts[j]);
      atomicAdd(&gsq [g0*ND + f4*4 + j], tq[j]);
    }
  }
}

// ---------------- finstats: 41 blocks (40 per-graph + 1 batch), pure-read, no reset ----------------
__global__ __launch_bounds__(256) void k_finstats(const float* __restrict__ gsum, const float* __restrict__ gsq,
                                                  const int* __restrict__ cnt, float* __restrict__ gmean,
                                                  float* __restrict__ grs, float* __restrict__ bnm,
                                                  float* __restrict__ bnrs){
  int d = threadIdx.x; // 256
  int b = blockIdx.x;
  if(b < NG){
    float c = (float)cnt[b];
    float s = gsum[b*ND + d], q = gsq[b*ND + d];
    float m = s / c;
    float v = q / c - m*m;
    gmean[b*ND + d] = m;
    grs[b*ND + d] = rsqrtf(fmaxf(v, 0.0f) + EPSF);
  } else {
    float ts = 0.0f, tq = 0.0f;
    for(int g = 0; g < NG; ++g){ ts += gsum[g*ND + d]; tq += gsq[g*ND + d]; }
    float bm = ts / (float)NN;
    float bv = tq / (float)NN - bm*bm;
    bnm[d] = bm;
    bnrs[d] = rsqrtf(fmaxf(bv, 0.0f) + EPSF);
  }
}

// ---------------- united norm apply (+ leaky) ----------------
// bf16 X in. LAYER<2: single bf16 out (residual AND next GEMM A, pad rows zeroed).
// LAYER==2: fp32 head_mean out.
template<int LAYER>
__global__ __launch_bounds__(256) void k_norm(const unsigned short* __restrict__ X, const int* __restrict__ gid,
    const float* __restrict__ gmean, const float* __restrict__ grs, const float* __restrict__ bnm,
    const float* __restrict__ bnrs, const float* __restrict__ gamma, const float* __restrict__ beta,
    const float* __restrict__ lbn, const float* __restrict__ lgn, const float* __restrict__ lnn,
    unsigned short* __restrict__ outb, float* __restrict__ outf){
  int n = blockIdx.x*4 + (threadIdx.x >> 6);
  int lane = threadIdx.x & 63;
  if(n >= NPAD) return;
  if(n >= NN){
    if(LAYER < 2){ uint2 z = {0,0}; ((uint2*)(outb + (size_t)n*ND))[lane] = z; }
    return;
  }
  float4 v = cvt4(((const ushort4*)(X + (size_t)n*ND))[lane]);
  float s = v.x + v.y + v.z + v.w;
  float q = v.x*v.x + v.y*v.y + v.z*v.z + v.w*v.w;
#pragma unroll
  for(int off = 32; off >= 1; off >>= 1){ s += __shfl_xor(s, off); q += __shfl_xor(q, off); }
  float nm = s * (1.0f/ND);
  float nv = q * (1.0f/ND) - nm*nm;
  float nrs = rsqrtf(fmaxf(nv, 0.0f) + EPSF);
  int g = gid[n];
  float4 gm = ((const float4*)(gmean + g*ND))[lane];
  float4 gr = ((const float4*)(grs   + g*ND))[lane];
  float4 bm = ((const float4*)bnm)[lane];
  float4 br = ((const float4*)bnrs)[lane];
  float4 ga = ((const float4*)gamma)[lane];
  float4 be = ((const float4*)beta)[lane];
  float4 lb = ((const float4*)lbn)[lane];
  float4 lg = ((const float4*)lgn)[lane];
  float4 ln = ((const float4*)lnn)[lane];
  float4 o;
  o.x = lrelu(ga.x*(lb.x*((v.x-bm.x)*br.x) + lg.x*((v.x-gm.x)*gr.x) + ln.x*((v.x-nm)*nrs)) + be.x);
  o.y = lrelu(ga.y*(lb.y*((v.y-bm.y)*br.y) + lg.y*((v.y-gm.y)*gr.y) + ln.y*((v.y-nm)*nrs)) + be.y);
  o.z = lrelu(ga.z*(lb.z*((v.z-bm.z)*br.z) + lg.z*((v.z-gm.z)*gr.z) + ln.z*((v.z-nm)*nrs)) + be.z);
  o.w = lrelu(ga.w*(lb.w*((v.w-bm.w)*br.w) + lg.w*((v.w-gm.w)*gr.w) + ln.w*((v.w-nm)*nrs)) + be.w);
  if(LAYER < 2){
    uint2 pk; pk.x = bfpair(o.x, o.y); pk.y = bfpair(o.z, o.w);
    ((uint2*)(outb + (size_t)n*ND))[lane] = pk;
  } else {
    float4 p;
    p.x = __shfl_xor(o.x, 32); p.y = __shfl_xor(o.y, 32);
    p.z = __shfl_xor(o.z, 32); p.w = __shfl_xor(o.w, 32);
    if(lane < 32){
      float4 hm;
      hm.x = 0.5f*(o.x + p.x); hm.y = 0.5f*(o.y + p.y);
      hm.z = 0.5f*(o.z + p.z); hm.w = 0.5f*(o.w + p.w);
      ((float4*)(outf + (size_t)n*NC))[lane] = hm;
    }
  }
}

// ---------------- graph readout ----------------
__global__ void k_readout_part(const float* __restrict__ HM, const int* __restrict__ gid,
                               const int* __restrict__ gmn, const int* __restrict__ gmx,
                               float* __restrict__ obuf){
  int g = blockIdx.x >> 3, part = blockIdx.x & 7;
  int c = threadIdx.x; // 128
  int n0 = gmn[g], n1 = gmx[g] + 1;
  int len = n1 - n0;
  int beg = n0 + (int)(((long)len * part) >> 3);
  int end = n0 + (int)(((long)len * (part+1)) >> 3);
  float acc = 0.0f;
  for(int n = beg; n < end; ++n){
    if(gid[n] == g) acc += HM[(size_t)n*NC + c];
  }
  atomicAdd(&obuf[g*NC + c], acc);
}

__global__ void k_readout_fin(const float* __restrict__ obuf, const int* __restrict__ cnt,
                              float* __restrict__ outp){
  int i = blockIdx.x*128 + threadIdx.x; // NG*NC
  int g = i / NC;
  outp[i] = lrelu(obuf[i] / (float)cnt[g]);
}

// ---------------- launch ----------------
extern "C" void kernel_launch(void* const* d_in, const int* in_sizes, int n_in,
                              void* d_out, int out_size, void* d_ws, size_t ws_size,
                              hipStream_t stream){
  const float* X0  = (const float*)d_in[0];
  const int* src   = (const int*)d_in[1];
  const int* dst   = (const int*)d_in[2];
  const int* gid   = (const int*)d_in[3];
  const float* Wm[3] = { (const float*)d_in[4], (const float*)d_in[5], (const float*)d_in[6] };
  const float* resW  = (const float*)d_in[7];
  const float *AL[3], *AR[3], *GA[3], *BE[3], *LB[3], *LG[3], *LN[3];
  for(int i = 0; i < 3; ++i){
    int b = 8 + i*7;
    AL[i] = (const float*)d_in[b];   AR[i] = (const float*)d_in[b+1];
    GA[i] = (const float*)d_in[b+2]; BE[i] = (const float*)d_in[b+3];
    LB[i] = (const float*)d_in[b+4]; LG[i] = (const float*)d_in[b+5]; LN[i] = (const float*)d_in[b+6];
  }
  float* out = (float*)d_out;

  // workspace layout (all node-feature intermediates bf16)
  float* wf = (float*)d_ws;
  unsigned short* Hbf  = (unsigned short*)wf;  wf += (size_t)NN*ND/2;    // h bf16
  unsigned short* XAb  = (unsigned short*)wf;  wf += (size_t)NN*ND/2;    // attn out bf16; L0 A-staging
  unsigned short* XBb  = (unsigned short*)wf;  wf += (size_t)NPAD*ND/2;  // norm out bf16 (residual + GEMM A)
  unsigned short* RESb = (unsigned short*)wf;  wf += (size_t)NN*ND/2;    // L0 residual bf16; later head_mean fp32
  float* el   = wf;                 wf += (size_t)NN*2;
  float* er   = wf;                 wf += (size_t)NN*2;
  float* gsum = wf;                 wf += 3*NG*ND;   // per-layer (no reset needed)
  float* gsq  = wf;                 wf += 3*NG*ND;
  float* gmean= wf;                 wf += NG*ND;
  float* grs  = wf;                 wf += NG*ND;
  float* bnm  = wf;                 wf += ND;
  float* bnrs = wf;                 wf += ND;
  float* obuf = wf;                 wf += NG*NC;
  unsigned short* Bt0 = (unsigned short*)wf; wf += (2*ND*NC)/2;   // 512x128 bf16
  unsigned short* Bt1 = (unsigned short*)wf; wf += (ND*ND)/2;     // 256x256 bf16
  unsigned short* Bt2 = (unsigned short*)wf; wf += (ND*ND)/2;     // 256x256 bf16
  int* ip = (int*)wf;
  int* deg      = ip;               ip += NN;
  int* rowstart = ip;               ip += NN + 1;
  int* cur      = ip;               ip += NN;
  int* srcS     = ip;               ip += NE;
  int* cnt      = ip;               ip += NG;
  int* gmn      = ip;               ip += NG;
  int* gmx      = ip;               ip += NG;
  int* bsum     = ip;               ip += SCAN_NB;
  int* boff     = ip;               ip += SCAN_NB;

  unsigned short* A0bf = XAb;            // L0 bf16 A staging (GEMM consumes before attn overwrites)
  float* HMf = (float*)RESb;             // L2 head_mean fp32 (NN*NC floats fit in NN*ND/2 ushort slots)

  // ---- prep (incl. zero-init) + CSR + graph meta ----
  k_prep<<<2600, 256, 0, stream>>>(X0, Wm[0], resW, Wm[1], Wm[2], (unsigned int*)A0bf, Bt0, Bt1, Bt2,
                                   deg, cur, cnt, gmn, gmx, gsum, gsq, obuf);
  k_hist<<<2500, 256, 0, stream>>>(dst, gid, deg, cnt, gmn, gmx);
  k_scan_a<<<SCAN_NB, 256, 0, stream>>>(deg, bsum);
  k_scan_b<<<1, 256, 0, stream>>>(bsum, boff, rowstart);
  k_scan_c<<<SCAN_NB, 256, 0, stream>>>(deg, boff, rowstart);
  k_fill<<<(NE+255)/256, 256, 0, stream>>>(src, dst, rowstart, cur, srcS);

  for(int L = 0; L < 3; ++L){
    float* gsumL = gsum + (size_t)L*NG*ND;
    float* gsqL  = gsq  + (size_t)L*NG*ND;
    if(L == 0){
      dim3 g0(NPAD/128, 2);  // by=0 -> h + el/er; by=1 -> residual
      k_gemm_bf16<NC,2><<<g0, 512, 0, stream>>>(A0bf, Bt0, RESb, Hbf, AL[0], AR[0], el, er);
    } else {
      dim3 g1(NPAD/128, 1);
      k_gemm_bf16<ND,1><<<g1, 512, 0, stream>>>(XBb, (L == 1) ? Bt1 : Bt2, nullptr, Hbf, AL[L], AR[L], el, er);
    }
    const unsigned short* resp = (L == 0) ? RESb : XBb;
    k_attn<<<NN/4, 256, 0, stream>>>(Hbf, el, er, rowstart, srcS, resp, XAb);
    k_gstats<<<NN/125, 256, 0, stream>>>(XAb, gid, gsumL, gsqL);
    k_finstats<<<NG+1, 256, 0, stream>>>(gsumL, gsqL, cnt, gmean, grs, bnm, bnrs);
    if(L == 0)      k_norm<0><<<NPAD/4, 256, 0, stream>>>(XAb, gid, gmean, grs, bnm, bnrs, GA[0], BE[0], LB[0], LG[0], LN[0], XBb, nullptr);
    else if(L == 1) k_norm<1><<<NPAD/4, 256, 0, stream>>>(XAb, gid, gmean, grs, bnm, bnrs, GA[1], BE[1], LB[1], LG[1], LN[1], XBb, nullptr);
    else            k_norm<2><<<NN/4, 256, 0, stream>>>(XAb, gid, gmean, grs, bnm, bnrs, GA[2], BE[2], LB[2], LG[2], LN[2], nullptr, HMf);
  }
  k_readout_part<<<NG*8, NC, 0, stream>>>(HMf, gid, gmn, gmx, obuf);
  k_readout_fin<<<NG, NC, 0, stream>>>(obuf, cnt, out);
}